// Round 13
// baseline (531.706 us; speedup 1.0000x reference)
//
#include <hip/hip_runtime.h>
#include <hip/hip_bf16.h>

#define D 128
#define N_TAXON 100000
#define N_SOTU 200000
#define E_HP 200000
#define E_RH 2000000
#define OUTC 64
#define NBUCK 98      // ceil(N_SOTU / 2048)
#define BSHIFT 11

typedef __hip_bfloat16 bf16;
typedef __bf16 bf16v8 __attribute__((ext_vector_type(8)));
typedef float f32x4 __attribute__((ext_vector_type(4)));
typedef int i32x4 __attribute__((ext_vector_type(4)));
typedef unsigned u32x2 __attribute__((ext_vector_type(2)));

union Frag { i32x4 i; bf16v8 v; };

__device__ __forceinline__ float bflo(unsigned u) { return __uint_as_float(u << 16); }
__device__ __forceinline__ float bfhi(unsigned u) { return __uint_as_float(u & 0xffff0000u); }

__device__ __forceinline__ unsigned short f2bf(float x) {
    unsigned u = __float_as_uint(x);
    unsigned r = (u + 0x7fffu + ((u >> 16) & 1u)) >> 16;   // round-to-nearest-even
    return (unsigned short)r;
}
__device__ __forceinline__ unsigned packbf(float a, float b) {
    return (unsigned)f2bf(a) | ((unsigned)f2bf(b) << 16);
}

// weight a-frag read from pre-swizzled global image; frag = Wt[col][32ks+8g..+7]
__device__ __forceinline__ i32x4 ldWfrag(const unsigned short* __restrict__ Wt,
                                         int col, int ks, int g) {
    int off = ((col << 8) + (ks << 6) + (g << 4)) ^ ((col & 7) << 4);
    return *(const i32x4*)((const char*)Wt + off);
}

// ---------------- fused: hp degree + rh bucket histogram ----------------
__global__ __launch_bounds__(256) void countAll_kernel(const int* __restrict__ hp_dst,
                                                       const int* __restrict__ rh_dst,
                                                       unsigned* __restrict__ cnt_t,
                                                       unsigned* __restrict__ bcnt)
{
    __shared__ unsigned hist[NBUCK];
    if (threadIdx.x < NBUCK) hist[threadIdx.x] = 0;
    __syncthreads();
    int stride = gridDim.x * 256;
    for (int e = blockIdx.x * 256 + threadIdx.x; e < E_HP; e += stride)
        atomicAdd(&cnt_t[hp_dst[e]], 1u);
    for (int e = blockIdx.x * 256 + threadIdx.x; e < E_RH; e += stride)
        atomicAdd(&hist[rh_dst[e] >> BSHIFT], 1u);
    __syncthreads();
    if (threadIdx.x < NBUCK) atomicAdd(&bcnt[threadIdx.x], hist[threadIdx.x]);
}

// ---------------- tiny bucket prefix (+ final row_ptr sentinel) ----------------
__global__ __launch_bounds__(128) void scan98_kernel(const unsigned* __restrict__ bcnt,
                                                     unsigned* __restrict__ bcursor,
                                                     unsigned* __restrict__ bstart,
                                                     unsigned* __restrict__ row_ptr)
{
    __shared__ unsigned v[NBUCK];
    if (threadIdx.x < NBUCK) v[threadIdx.x] = bcnt[threadIdx.x];
    __syncthreads();
    if (threadIdx.x == 0) {
        unsigned acc = 0;
        for (int b = 0; b < NBUCK; ++b) {
            unsigned t = v[b];
            bcursor[b] = acc; bstart[b] = acc; acc += t;
        }
        bstart[NBUCK] = acc;
        row_ptr[N_TAXON + N_SOTU] = E_HP + acc;   // sentinel
    }
}

// ---------------- rh: partition edges into dst-buckets ----------------
__global__ __launch_bounds__(256) void partition_kernel(
    const int* __restrict__ src, const int* __restrict__ dst,
    unsigned* __restrict__ bcursor, unsigned long long* __restrict__ ebuf, int n)
{
    __shared__ unsigned hist[NBUCK];
    __shared__ unsigned lcur[NBUCK];
    int base = blockIdx.x * 4096;
    if (threadIdx.x < NBUCK) hist[threadIdx.x] = 0;
    __syncthreads();
    int s[16], d[16];
#pragma unroll
    for (int k = 0; k < 16; ++k) {
        int e = base + k * 256 + threadIdx.x;
        if (e < n) {
            s[k] = src[e]; d[k] = dst[e];
            atomicAdd(&hist[d[k] >> BSHIFT], 1u);
        } else d[k] = -1;
    }
    __syncthreads();
    if (threadIdx.x < NBUCK)
        lcur[threadIdx.x] = atomicAdd(&bcursor[threadIdx.x], hist[threadIdx.x]);
    __syncthreads();
#pragma unroll
    for (int k = 0; k < 16; ++k) {
        if (d[k] >= 0) {
            unsigned slot = atomicAdd(&lcur[d[k] >> BSHIFT], 1u);
            ebuf[slot] = ((unsigned long long)(unsigned)d[k] << 32) | (unsigned)s[k];
        }
    }
}

// ---------------- hp-only 3-phase exclusive scan ----------------
__global__ __launch_bounds__(256) void scanA_kernel(const unsigned* __restrict__ cnt,
                                                    unsigned* __restrict__ bsum, int n)
{
    int lane = threadIdx.x & 63, wv = threadIdx.x >> 6;
    __shared__ unsigned ws[4];
    int i = blockIdx.x * 256 + threadIdx.x;
    unsigned v = (i < n) ? cnt[i] : 0u;
    for (int off = 1; off < 64; off <<= 1) v += __shfl_xor(v, off, 64);
    if (lane == 0) ws[wv] = v;
    __syncthreads();
    if (threadIdx.x == 0) bsum[blockIdx.x] = ws[0] + ws[1] + ws[2] + ws[3];
}

__global__ __launch_bounds__(1024) void scanB_kernel(unsigned* __restrict__ bsum, int nb,
                                                     unsigned* __restrict__ total_out)
{
    int lane = threadIdx.x & 63, wv = threadIdx.x >> 6;
    __shared__ unsigned wsum[16];
    int t = threadIdx.x;
    unsigned v0 = (2 * t     < nb) ? bsum[2 * t]     : 0u;
    unsigned v1 = (2 * t + 1 < nb) ? bsum[2 * t + 1] : 0u;
    unsigned v = v0 + v1;
    unsigned s = v;
    for (int off = 1; off < 64; off <<= 1) {
        unsigned tt = __shfl_up(s, off, 64);
        if (lane >= off) s += tt;
    }
    if (lane == 63) wsum[wv] = s;
    __syncthreads();
    unsigned woff = 0, tot = 0;
    for (int w = 0; w < 16; ++w) { if (w < wv) woff += wsum[w]; tot += wsum[w]; }
    unsigned ex = woff + s - v;
    if (2 * t     < nb) bsum[2 * t]     = ex;
    if (2 * t + 1 < nb) bsum[2 * t + 1] = ex + v0;
    if (t == 0) *total_out = tot;
}

__global__ __launch_bounds__(256) void scanC_kernel(const unsigned* __restrict__ cnt,
                                                    const unsigned* __restrict__ bsum,
                                                    unsigned* __restrict__ row_ptr,
                                                    unsigned* __restrict__ cursor, int n)
{
    int lane = threadIdx.x & 63, wv = threadIdx.x >> 6;
    __shared__ unsigned wsum[4];
    int i = blockIdx.x * 256 + threadIdx.x;
    unsigned v = (i < n) ? cnt[i] : 0u;
    unsigned s = v;
    for (int off = 1; off < 64; off <<= 1) {
        unsigned t = __shfl_up(s, off, 64);
        if (lane >= off) s += t;
    }
    if (lane == 63) wsum[wv] = s;
    __syncthreads();
    unsigned woff = bsum[blockIdx.x];
    for (int w = 0; w < wv; ++w) woff += wsum[w];
    if (i < n) { unsigned p = woff + s - v; row_ptr[i] = p; cursor[i] = p; }
}

// ---------------- hp CSR fill ----------------
__global__ __launch_bounds__(256) void fill_hp_kernel(const int* __restrict__ src,
                                                      const int* __restrict__ dst,
                                                      unsigned* __restrict__ cursor,
                                                      int* __restrict__ sorted_all)
{
    int stride = gridDim.x * 256;
    for (int i = blockIdx.x * 256 + threadIdx.x; i < E_HP; i += stride) {
        unsigned pos = atomicAdd(&cursor[dst[i]], 1u);
        sorted_all[pos] = src[i];
    }
}

// ---------------- rh CSR fill: per-bucket LDS count + scan + row_ptr + fill ----------------
__global__ __launch_bounds__(256) void fillB_kernel(const unsigned long long* __restrict__ ebuf,
                                                    const unsigned* __restrict__ bstart,
                                                    unsigned* __restrict__ row_ptr,
                                                    int* __restrict__ sorted_all)
{
    __shared__ unsigned hist[1 << BSHIFT];   // 8KB: counts -> absolute cursors
    __shared__ unsigned wsum[4];
    int c = blockIdx.x;
    int dbase = c << BSHIFT;
    for (int i = threadIdx.x; i < (1 << BSHIFT); i += 256) hist[i] = 0;
    __syncthreads();
    unsigned e0 = bstart[c], e1 = bstart[c + 1];
    for (unsigned e = e0 + threadIdx.x; e < e1; e += 256)
        atomicAdd(&hist[(unsigned)(ebuf[e] >> 32) - dbase], 1u);
    __syncthreads();
    int base8 = threadIdx.x * 8;
    unsigned loc[8], s = 0;
#pragma unroll
    for (int i = 0; i < 8; ++i) { loc[i] = s; s += hist[base8 + i]; }
    int lane = threadIdx.x & 63, wv = threadIdx.x >> 6;
    unsigned sc = s;
    for (int off = 1; off < 64; off <<= 1) {
        unsigned t = __shfl_up(sc, off, 64);
        if (lane >= off) sc += t;
    }
    if (lane == 63) wsum[wv] = sc;
    __syncthreads();
    unsigned woff = 0;
    for (int w = 0; w < wv; ++w) woff += wsum[w];
    unsigned tbase = E_HP + e0 + woff + sc - s;
#pragma unroll
    for (int i = 0; i < 8; ++i) {
        int dd = dbase + base8 + i;
        unsigned p = tbase + loc[i];
        if (dd < N_SOTU) row_ptr[N_TAXON + dd] = p;
        hist[base8 + i] = p;
    }
    __syncthreads();
    for (unsigned e = e0 + threadIdx.x; e < e1; e += 256) {
        unsigned long long v = ebuf[e];
        unsigned pos = atomicAdd(&hist[(unsigned)(v >> 32) - dbase], 1u);
        sorted_all[pos] = (int)(unsigned)v;
    }
}

// ---------------- all weights: transpose + bf16 + XOR-swizzle ----------------
__global__ __launch_bounds__(256) void wprep_all_kernel(
    const float* __restrict__ W1l, const float* __restrict__ W1r,
    const float* __restrict__ W2l, const float* __restrict__ W2r,
    const float* __restrict__ W3l, const float* __restrict__ W3r,
    const float* __restrict__ Wlin, unsigned short* __restrict__ wtbase)
{
    int e = blockIdx.x * 256 + threadIdx.x;
    if (e >= 6 * 16384 + 8192) return;
    const float* srcs[7] = { W1l, W1r, W2l, W2r, W3l, W3r, Wlin };
    int m = e >> 14;
    int local = (m < 6) ? (e & 16383) : (e - 98304);
    int N = (m < 6) ? 128 : 64;
    int k = local / N, col = local - k * N;
    unsigned short* dst = wtbase + ((m < 6) ? m * 16384 : 98304);
    dst[(col * 128 + k) ^ ((col & 7) << 3)] = f2bf(srcs[m][local]);
}

// ---------------- hp mean gather from f32 x_taxon (XCD-swizzled) ----------------
__global__ __launch_bounds__(256) void aggMeanHp_kernel(
    const float* __restrict__ x, const unsigned* __restrict__ rp,
    const int* __restrict__ nbr, unsigned* __restrict__ outm)
{
    int wave = threadIdx.x >> 6, lane = threadIdx.x & 63;
    int bid = (blockIdx.x & 7) * 3125 + (blockIdx.x >> 3);   // grid = 25000
    int r = bid * 4 + wave;
    unsigned beg = rp[r], end = rp[r + 1];
    float a0 = 0.f, a1 = 0.f;
    unsigned u = beg;
    for (; u + 2 <= end; u += 2) {
        float2 A = ((const float2*)x)[(size_t)nbr[u] * 64 + lane];
        float2 B = ((const float2*)x)[(size_t)nbr[u + 1] * 64 + lane];
        a0 += A.x + B.x; a1 += A.y + B.y;
    }
    if (u < end) {
        float2 A = ((const float2*)x)[(size_t)nbr[u] * 64 + lane];
        a0 += A.x; a1 += A.y;
    }
    unsigned c = end - beg;
    float inv = 1.f / (float)(c ? c : 1u);
    outm[(size_t)r * 64 + lane] = packbf(a0 * inv, a1 * inv);
}

// ---------------- taxon_h GEMM; writes FULL X2 rows (even = bf16(x), odd = taxon_h) ----------------
__global__ __launch_bounds__(256) void gemmTh_kernel(
    const unsigned* __restrict__ A1 /*meanX_hp*/, const float* __restrict__ X /*x_taxon f32*/,
    const unsigned short* __restrict__ WtA, const unsigned short* __restrict__ WtB,
    const float* __restrict__ bias, unsigned* __restrict__ X2, int M)
{
    __shared__ char sW[65536];
    for (int c = threadIdx.x; c < 4096; c += 256)
        ((i32x4*)sW)[c] = (c < 2048) ? ((const i32x4*)WtA)[c] : ((const i32x4*)WtB)[c - 2048];
    __syncthreads();

    int wave = threadIdx.x >> 6, lane = threadIdx.x & 63;
    int ln = lane & 15, g = lane >> 4;
    int row = blockIdx.x * 64 + wave * 16 + ln;
    int rl = row < M ? row : M - 1;
    int swz = (ln & 7) << 4;

    f32x4 acc[8];
#pragma unroll
    for (int cf = 0; cf < 8; ++cf) acc[cf] = ((const f32x4*)bias)[cf * 4 + g];

    const i32x4* a1r = (const i32x4*)(A1 + (size_t)rl * 64);
    const f32x4* xr = (const f32x4*)(X + (size_t)rl * 128);
    unsigned* orow = X2 + (size_t)row * 128;
    i32x4 xpk[4];
#pragma unroll
    for (int ks = 0; ks < 4; ++ks) {
        Frag mf; mf.i = a1r[ks * 4 + g];
        f32x4 fa = xr[ks * 8 + g * 2], fb = xr[ks * 8 + g * 2 + 1];
        Frag xf;
        i32x4 t = { (int)packbf(fa.x, fa.y), (int)packbf(fa.z, fa.w),
                    (int)packbf(fb.x, fb.y), (int)packbf(fb.z, fb.w) };
        xf.i = t; xpk[ks] = t;
#pragma unroll
        for (int cf = 0; cf < 8; ++cf) {
            int off = (((cf * 16 + ln) << 8) + (ks << 6) + (g << 4)) ^ swz;
            Frag wa; wa.i = *(const i32x4*)(sW + off);
            Frag wb; wb.i = *(const i32x4*)(sW + 32768 + off);
            acc[cf] = __builtin_amdgcn_mfma_f32_16x16x32_bf16(wa.v, mf.v, acc[cf], 0, 0, 0);
            acc[cf] = __builtin_amdgcn_mfma_f32_16x16x32_bf16(wb.v, xf.v, acc[cf], 0, 0, 0);
        }
    }

    if (row < M) {
#pragma unroll
        for (int ks = 0; ks < 4; ++ks) {
            int p0 = 16 * ks + 4 * g;
            orow[(p0 + 0) * 2] = (unsigned)xpk[ks][0];
            orow[(p0 + 1) * 2] = (unsigned)xpk[ks][1];
            orow[(p0 + 2) * 2] = (unsigned)xpk[ks][2];
            orow[(p0 + 3) * 2] = (unsigned)xpk[ks][3];
        }
#pragma unroll
        for (int cf = 0; cf < 8; ++cf) {
            int p = cf * 8 + g * 2;
            orow[p * 2 + 1]       = packbf(fmaxf(acc[cf][0], 0.f), fmaxf(acc[cf][1], 0.f));
            orow[(p + 1) * 2 + 1] = packbf(fmaxf(acc[cf][2], 0.f), fmaxf(acc[cf][3], 0.f));
        }
    }
}

// ---------------- merged rh gather: meanXrh + meanH in ONE walk (XCD-swizzled) ----------------
__global__ __launch_bounds__(256) void aggMean2_kernel(
    const unsigned* __restrict__ X2, const unsigned* __restrict__ rp,
    const int* __restrict__ nbr,
    unsigned* __restrict__ meanXrh, unsigned* __restrict__ meanH)
{
    int wave = threadIdx.x >> 6, lane = threadIdx.x & 63;
    int bid = (blockIdx.x & 7) * 6250 + (blockIdx.x >> 3);   // grid = 50000
    int r = bid * 4 + wave;
    unsigned beg = rp[r], end = rp[r + 1];
    float a0 = 0.f, a1 = 0.f, a2 = 0.f, a3 = 0.f;
    unsigned u = beg;
    for (; u + 2 <= end; u += 2) {
        int j0 = nbr[u], j1 = nbr[u + 1];
        u32x2 A = *(const u32x2*)(X2 + (size_t)j0 * 128 + lane * 2);
        u32x2 B = *(const u32x2*)(X2 + (size_t)j1 * 128 + lane * 2);
        a0 += bflo(A.x) + bflo(B.x); a1 += bfhi(A.x) + bfhi(B.x);
        a2 += bflo(A.y) + bflo(B.y); a3 += bfhi(A.y) + bfhi(B.y);
    }
    if (u < end) {
        u32x2 A = *(const u32x2*)(X2 + (size_t)nbr[u] * 128 + lane * 2);
        a0 += bflo(A.x); a1 += bfhi(A.x); a2 += bflo(A.y); a3 += bfhi(A.y);
    }
    unsigned c = end - beg;
    float inv = 1.f / (float)(c ? c : 1u);
    meanXrh[(size_t)r * 64 + lane] = packbf(a0 * inv, a1 * inv);
    meanH[(size_t)r * 64 + lane]   = packbf(a2 * inv, a3 * inv);
}

// ---------------- gemmSh: sotu_h = relu(meanXrh@W2l + x_sotu@W2r + b2), LDS weights ----------------
__global__ __launch_bounds__(256) void gemmSh_kernel(
    const unsigned* __restrict__ A1 /*meanXrh*/, const float* __restrict__ X /*x_sotu f32*/,
    const unsigned short* __restrict__ WtA, const unsigned short* __restrict__ WtB,
    const float* __restrict__ bias, unsigned* __restrict__ Yout, int M)
{
    __shared__ char sW[65536];
    for (int c = threadIdx.x; c < 4096; c += 256)
        ((i32x4*)sW)[c] = (c < 2048) ? ((const i32x4*)WtA)[c] : ((const i32x4*)WtB)[c - 2048];
    __syncthreads();

    int wave = threadIdx.x >> 6, lane = threadIdx.x & 63;
    int ln = lane & 15, g = lane >> 4;
    int row = blockIdx.x * 64 + wave * 16 + ln;
    int rl = row < M ? row : M - 1;
    int swz = (ln & 7) << 4;

    f32x4 acc[8];
#pragma unroll
    for (int cf = 0; cf < 8; ++cf) acc[cf] = ((const f32x4*)bias)[cf * 4 + g];

    const i32x4* a1r = (const i32x4*)(A1 + (size_t)rl * 64);
    const f32x4* xr = (const f32x4*)(X + (size_t)rl * 128);
#pragma unroll
    for (int ks = 0; ks < 4; ++ks) {
        Frag mf; mf.i = a1r[ks * 4 + g];
        f32x4 fa = xr[ks * 8 + g * 2], fb = xr[ks * 8 + g * 2 + 1];
        Frag xf;
        i32x4 t = { (int)packbf(fa.x, fa.y), (int)packbf(fa.z, fa.w),
                    (int)packbf(fb.x, fb.y), (int)packbf(fb.z, fb.w) };
        xf.i = t;
#pragma unroll
        for (int cf = 0; cf < 8; ++cf) {
            int off = (((cf * 16 + ln) << 8) + (ks << 6) + (g << 4)) ^ swz;
            Frag wa; wa.i = *(const i32x4*)(sW + off);
            Frag wb; wb.i = *(const i32x4*)(sW + 32768 + off);
            acc[cf] = __builtin_amdgcn_mfma_f32_16x16x32_bf16(wa.v, mf.v, acc[cf], 0, 0, 0);
            acc[cf] = __builtin_amdgcn_mfma_f32_16x16x32_bf16(wb.v, xf.v, acc[cf], 0, 0, 0);
        }
    }

    if (row < M) {
        unsigned* orow = Yout + (size_t)row * 64;
#pragma unroll
        for (int cf = 0; cf < 8; ++cf) {
            u32x2 o;
            o.x = packbf(fmaxf(acc[cf][0], 0.f), fmaxf(acc[cf][1], 0.f));
            o.y = packbf(fmaxf(acc[cf][2], 0.f), fmaxf(acc[cf][3], 0.f));
            *(u32x2*)(orow + cf * 8 + g * 2) = o;
        }
    }
}

// ---------------- tailB: h2 = relu(meanH@W3l + sotu_h@W3r + b3) (LDS weights + LDS h2) -> out ----------------
__global__ __launch_bounds__(256) void tailB_kernel(
    const unsigned* __restrict__ meanH, const unsigned* __restrict__ sotu_h,
    const unsigned short* __restrict__ Wt3l, const unsigned short* __restrict__ Wt3r,
    const unsigned short* __restrict__ Wtlin,
    const float* __restrict__ b3, const float* __restrict__ blin,
    float* __restrict__ out)
{
    __shared__ char sW[65536];         // W3l | W3r
    __shared__ unsigned h2[64 * 64];   // 16KB, XOR-swizzled
    for (int c = threadIdx.x; c < 4096; c += 256)
        ((i32x4*)sW)[c] = (c < 2048) ? ((const i32x4*)Wt3l)[c] : ((const i32x4*)Wt3r)[c - 2048];
    __syncthreads();

    int wave = threadIdx.x >> 6, lane = threadIdx.x & 63;
    int ln = lane & 15, g = lane >> 4;
    int lrow = wave * 16 + ln;
    int row = blockIdx.x * 64 + lrow;
    int swzW = (ln & 7) << 4;
    int swz = (lrow & 7) << 2;

    // stage 1: h2 = relu(meanH@W3l + sotu_h@W3r + b3)
    f32x4 acc[8];
#pragma unroll
    for (int cf = 0; cf < 8; ++cf) acc[cf] = ((const f32x4*)b3)[cf * 4 + g];
    {
        const i32x4* mr = (const i32x4*)(meanH + (size_t)row * 64);
        const i32x4* sr = (const i32x4*)(sotu_h + (size_t)row * 64);
#pragma unroll
        for (int ks = 0; ks < 4; ++ks) {
            Frag mf; mf.i = mr[ks * 4 + g];
            Frag sf; sf.i = sr[ks * 4 + g];
#pragma unroll
            for (int cf = 0; cf < 8; ++cf) {
                int off = (((cf * 16 + ln) << 8) + (ks << 6) + (g << 4)) ^ swzW;
                Frag wl; wl.i = *(const i32x4*)(sW + off);
                Frag wr; wr.i = *(const i32x4*)(sW + 32768 + off);
                acc[cf] = __builtin_amdgcn_mfma_f32_16x16x32_bf16(wl.v, mf.v, acc[cf], 0, 0, 0);
                acc[cf] = __builtin_amdgcn_mfma_f32_16x16x32_bf16(wr.v, sf.v, acc[cf], 0, 0, 0);
            }
        }
    }
#pragma unroll
    for (int cf = 0; cf < 8; ++cf) {
        u32x2 o;
        o.x = packbf(fmaxf(acc[cf][0], 0.f), fmaxf(acc[cf][1], 0.f));
        o.y = packbf(fmaxf(acc[cf][2], 0.f), fmaxf(acc[cf][3], 0.f));
        *(u32x2*)&h2[lrow * 64 + ((cf * 8 + g * 2) ^ swz)] = o;
    }
    __syncthreads();

    // stage 2: out = h2 @ Wlin + blin (Wlin from global, only 16 frags/wave)
    f32x4 aL[4];
#pragma unroll
    for (int cf = 0; cf < 4; ++cf) aL[cf] = ((const f32x4*)blin)[cf * 4 + g];
#pragma unroll
    for (int ks = 0; ks < 4; ++ks) {
        Frag hf; hf.i = *(const i32x4*)&h2[lrow * 64 + ((ks * 16 + g * 4) ^ swz)];
#pragma unroll
        for (int cf = 0; cf < 4; ++cf) {
            Frag wf; wf.i = ldWfrag(Wtlin, cf * 16 + ln, ks, g);
            aL[cf] = __builtin_amdgcn_mfma_f32_16x16x32_bf16(wf.v, hf.v, aL[cf], 0, 0, 0);
        }
    }
    float* orow = out + (size_t)row * OUTC;
#pragma unroll
    for (int cf = 0; cf < 4; ++cf)
        *(f32x4*)(orow + cf * 16 + g * 4) = aL[cf];
}

extern "C" void kernel_launch(void* const* d_in, const int* in_sizes, int n_in,
                              void* d_out, int out_size, void* d_ws, size_t ws_size,
                              hipStream_t stream)
{
    const float* x_taxon = (const float*)d_in[0];
    const float* x_sotu  = (const float*)d_in[1];
    const int* hp_src = (const int*)d_in[2];
    const int* hp_dst = (const int*)d_in[3];
    const int* rh_src = (const int*)d_in[4];
    const int* rh_dst = (const int*)d_in[5];
    const float* W1l = (const float*)d_in[6];
    const float* W1r = (const float*)d_in[7];
    const float* b1  = (const float*)d_in[8];
    const float* W2l = (const float*)d_in[9];
    const float* W2r = (const float*)d_in[10];
    const float* b2  = (const float*)d_in[11];
    const float* W3l = (const float*)d_in[12];
    const float* W3r = (const float*)d_in[13];
    const float* b3  = (const float*)d_in[14];
    const float* Wlin = (const float*)d_in[15];
    const float* blin = (const float*)d_in[16];
    float* out = (float*)d_out;

    // ---- workspace layout (bytes), peak ~190.3 MB ----
    char* ws = (char*)d_ws;
    unsigned* X2      = (unsigned*)(ws);                  // [100K][128]; sotu_h overlays after aggMean2
    unsigned* sotu_h  = (unsigned*)(ws);                  // [200K][64] (X2 dead by then)
    unsigned* meanXrh = (unsigned*)(ws + 51200000);       // [200K][64]; ebuf overlays (dead first)
    unsigned* meanH   = (unsigned*)(ws + 102400000);      // [200K][64]
    unsigned* meanX_hp= (unsigned*)(ws + 153600000);      // [100K][64]
    unsigned long long* ebuf = (unsigned long long*)(ws + 51200000);  // 16MB, dead before aggMean2
    int*      sorted_all = (int*)(ws + 179200000);        // 8.8MB
    unsigned* row_ptr = (unsigned*)(ws + 188000000);      // [300001]
    unsigned* cursor  = (unsigned*)(ws + 189200128);      // [100000]
    unsigned* cnt_t   = (unsigned*)(ws + 189600128);      // [100000]
    unsigned* bcnt    = (unsigned*)(ws + 190000128);      // [128]
    unsigned* bcursor = (unsigned*)(ws + 190000640);      // [128]
    unsigned* bstart  = (unsigned*)(ws + 190001152);      // [128]
    unsigned* bsum    = (unsigned*)(ws + 190001664);      // [2048]
    unsigned short* wtbase = (unsigned short*)(ws + 190009856);
    unsigned short* Wt1l = wtbase;
    unsigned short* Wt1r = wtbase + 16384;
    unsigned short* Wt2l = wtbase + 32768;
    unsigned short* Wt2r = wtbase + 49152;
    unsigned short* Wt3l = wtbase + 65536;
    unsigned short* Wt3r = wtbase + 81920;
    unsigned short* Wtlin = wtbase + 98304;

    // zero cnt_t [100000] + bcnt [128] (contiguous)
    hipMemsetAsync(cnt_t, 0, 100000 * 4 + 512, stream);

    // ---- CSR build ----
    countAll_kernel<<<256, 256, 0, stream>>>(hp_dst, rh_dst, cnt_t, bcnt);
    scan98_kernel<<<1, 128, 0, stream>>>(bcnt, bcursor, bstart, row_ptr);
    partition_kernel<<<(E_RH + 4095) / 4096, 256, 0, stream>>>(rh_src, rh_dst, bcursor, ebuf, E_RH);
    {
        int nb = (N_TAXON + 255) / 256;   // 391
        scanA_kernel<<<nb, 256, 0, stream>>>(cnt_t, bsum, N_TAXON);
        scanB_kernel<<<1, 1024, 0, stream>>>(bsum, nb, row_ptr + N_TAXON);
        scanC_kernel<<<nb, 256, 0, stream>>>(cnt_t, bsum, row_ptr, cursor, N_TAXON);
    }
    fill_hp_kernel<<<782, 256, 0, stream>>>(hp_src, hp_dst, cursor, sorted_all);
    fillB_kernel<<<NBUCK, 256, 0, stream>>>(ebuf, bstart, row_ptr, sorted_all);

    // ---- weight prep ----
    wprep_all_kernel<<<(6 * 16384 + 8192 + 255) / 256, 256, 0, stream>>>(
        W1l, W1r, W2l, W2r, W3l, W3r, Wlin, wtbase);

    // ---- meanX_hp over hp CSR (f32 source) ----
    aggMeanHp_kernel<<<N_TAXON / 4, 256, 0, stream>>>(x_taxon, row_ptr, sorted_all, meanX_hp);

    // ---- taxon_h GEMM -> full X2 rows ----
    gemmTh_kernel<<<(N_TAXON + 63) / 64, 256, 0, stream>>>(
        meanX_hp, x_taxon, Wt1l, Wt1r, b1, X2, N_TAXON);

    // ---- merged rh gather: meanXrh + meanH in one walk ----
    aggMean2_kernel<<<N_SOTU / 4, 256, 0, stream>>>(
        X2, row_ptr + N_TAXON, sorted_all, meanXrh, meanH);

    // ---- sotu_h = relu(meanXrh@W2l + x_sotu@W2r + b2)  (LDS weights; overlays X2) ----
    gemmSh_kernel<<<N_SOTU / 64, 256, 0, stream>>>(
        meanXrh, x_sotu, Wt2l, Wt2r, b2, sotu_h, N_SOTU);

    // ---- tailB: h2 (LDS) -> out ----
    tailB_kernel<<<N_SOTU / 64, 256, 0, stream>>>(
        meanH, sotu_h, Wt3l, Wt3r, Wtlin, b3, blin, out);
}

// Round 14
// 458.727 us; speedup vs baseline: 1.1591x; 1.1591x over previous
//
#include <hip/hip_runtime.h>
#include <hip/hip_bf16.h>

#define D 128
#define N_TAXON 100000
#define N_SOTU 200000
#define E_HP 200000
#define E_RH 2000000
#define OUTC 64
#define NBUCK 98      // ceil(N_SOTU / 2048)
#define BSHIFT 11

typedef __hip_bfloat16 bf16;
typedef __bf16 bf16v8 __attribute__((ext_vector_type(8)));
typedef float f32x4 __attribute__((ext_vector_type(4)));
typedef int i32x4 __attribute__((ext_vector_type(4)));
typedef unsigned u32x2 __attribute__((ext_vector_type(2)));

union Frag { i32x4 i; bf16v8 v; };

__device__ __forceinline__ float bflo(unsigned u) { return __uint_as_float(u << 16); }
__device__ __forceinline__ float bfhi(unsigned u) { return __uint_as_float(u & 0xffff0000u); }

__device__ __forceinline__ unsigned short f2bf(float x) {
    unsigned u = __float_as_uint(x);
    unsigned r = (u + 0x7fffu + ((u >> 16) & 1u)) >> 16;   // round-to-nearest-even
    return (unsigned short)r;
}
__device__ __forceinline__ unsigned packbf(float a, float b) {
    return (unsigned)f2bf(a) | ((unsigned)f2bf(b) << 16);
}

// ---------------- fused: hp degree + rh bucket histogram ----------------
__global__ __launch_bounds__(256) void countAll_kernel(const int* __restrict__ hp_dst,
                                                       const int* __restrict__ rh_dst,
                                                       unsigned* __restrict__ cnt_t,
                                                       unsigned* __restrict__ bcnt)
{
    __shared__ unsigned hist[NBUCK];
    if (threadIdx.x < NBUCK) hist[threadIdx.x] = 0;
    __syncthreads();
    int stride = gridDim.x * 256;
    for (int e = blockIdx.x * 256 + threadIdx.x; e < E_HP; e += stride)
        atomicAdd(&cnt_t[hp_dst[e]], 1u);
    for (int e = blockIdx.x * 256 + threadIdx.x; e < E_RH; e += stride)
        atomicAdd(&hist[rh_dst[e] >> BSHIFT], 1u);
    __syncthreads();
    if (threadIdx.x < NBUCK) atomicAdd(&bcnt[threadIdx.x], hist[threadIdx.x]);
}

// ---------------- tiny bucket prefix (+ final row_ptr sentinel) ----------------
__global__ __launch_bounds__(128) void scan98_kernel(const unsigned* __restrict__ bcnt,
                                                     unsigned* __restrict__ bcursor,
                                                     unsigned* __restrict__ bstart,
                                                     unsigned* __restrict__ row_ptr)
{
    __shared__ unsigned v[NBUCK];
    if (threadIdx.x < NBUCK) v[threadIdx.x] = bcnt[threadIdx.x];
    __syncthreads();
    if (threadIdx.x == 0) {
        unsigned acc = 0;
        for (int b = 0; b < NBUCK; ++b) {
            unsigned t = v[b];
            bcursor[b] = acc; bstart[b] = acc; acc += t;
        }
        bstart[NBUCK] = acc;
        row_ptr[N_TAXON + N_SOTU] = E_HP + acc;   // sentinel
    }
}

// ---------------- rh: partition edges into dst-buckets ----------------
__global__ __launch_bounds__(256) void partition_kernel(
    const int* __restrict__ src, const int* __restrict__ dst,
    unsigned* __restrict__ bcursor, unsigned long long* __restrict__ ebuf, int n)
{
    __shared__ unsigned hist[NBUCK];
    __shared__ unsigned lcur[NBUCK];
    int base = blockIdx.x * 4096;
    if (threadIdx.x < NBUCK) hist[threadIdx.x] = 0;
    __syncthreads();
    int s[16], d[16];
#pragma unroll
    for (int k = 0; k < 16; ++k) {
        int e = base + k * 256 + threadIdx.x;
        if (e < n) {
            s[k] = src[e]; d[k] = dst[e];
            atomicAdd(&hist[d[k] >> BSHIFT], 1u);
        } else d[k] = -1;
    }
    __syncthreads();
    if (threadIdx.x < NBUCK)
        lcur[threadIdx.x] = atomicAdd(&bcursor[threadIdx.x], hist[threadIdx.x]);
    __syncthreads();
#pragma unroll
    for (int k = 0; k < 16; ++k) {
        if (d[k] >= 0) {
            unsigned slot = atomicAdd(&lcur[d[k] >> BSHIFT], 1u);
            ebuf[slot] = ((unsigned long long)(unsigned)d[k] << 32) | (unsigned)s[k];
        }
    }
}

// ---------------- hp-only 3-phase exclusive scan ----------------
__global__ __launch_bounds__(256) void scanA_kernel(const unsigned* __restrict__ cnt,
                                                    unsigned* __restrict__ bsum, int n)
{
    int lane = threadIdx.x & 63, wv = threadIdx.x >> 6;
    __shared__ unsigned ws[4];
    int i = blockIdx.x * 256 + threadIdx.x;
    unsigned v = (i < n) ? cnt[i] : 0u;
    for (int off = 1; off < 64; off <<= 1) v += __shfl_xor(v, off, 64);
    if (lane == 0) ws[wv] = v;
    __syncthreads();
    if (threadIdx.x == 0) bsum[blockIdx.x] = ws[0] + ws[1] + ws[2] + ws[3];
}

__global__ __launch_bounds__(1024) void scanB_kernel(unsigned* __restrict__ bsum, int nb,
                                                     unsigned* __restrict__ total_out)
{
    int lane = threadIdx.x & 63, wv = threadIdx.x >> 6;
    __shared__ unsigned wsum[16];
    int t = threadIdx.x;
    unsigned v0 = (2 * t     < nb) ? bsum[2 * t]     : 0u;
    unsigned v1 = (2 * t + 1 < nb) ? bsum[2 * t + 1] : 0u;
    unsigned v = v0 + v1;
    unsigned s = v;
    for (int off = 1; off < 64; off <<= 1) {
        unsigned tt = __shfl_up(s, off, 64);
        if (lane >= off) s += tt;
    }
    if (lane == 63) wsum[wv] = s;
    __syncthreads();
    unsigned woff = 0, tot = 0;
    for (int w = 0; w < 16; ++w) { if (w < wv) woff += wsum[w]; tot += wsum[w]; }
    unsigned ex = woff + s - v;
    if (2 * t     < nb) bsum[2 * t]     = ex;
    if (2 * t + 1 < nb) bsum[2 * t + 1] = ex + v0;
    if (t == 0) *total_out = tot;
}

__global__ __launch_bounds__(256) void scanC_kernel(const unsigned* __restrict__ cnt,
                                                    const unsigned* __restrict__ bsum,
                                                    unsigned* __restrict__ row_ptr,
                                                    unsigned* __restrict__ cursor, int n)
{
    int lane = threadIdx.x & 63, wv = threadIdx.x >> 6;
    __shared__ unsigned wsum[4];
    int i = blockIdx.x * 256 + threadIdx.x;
    unsigned v = (i < n) ? cnt[i] : 0u;
    unsigned s = v;
    for (int off = 1; off < 64; off <<= 1) {
        unsigned t = __shfl_up(s, off, 64);
        if (lane >= off) s += t;
    }
    if (lane == 63) wsum[wv] = s;
    __syncthreads();
    unsigned woff = bsum[blockIdx.x];
    for (int w = 0; w < wv; ++w) woff += wsum[w];
    if (i < n) { unsigned p = woff + s - v; row_ptr[i] = p; cursor[i] = p; }
}

// ---------------- hp CSR fill ----------------
__global__ __launch_bounds__(256) void fill_hp_kernel(const int* __restrict__ src,
                                                      const int* __restrict__ dst,
                                                      unsigned* __restrict__ cursor,
                                                      int* __restrict__ sorted_all)
{
    int stride = gridDim.x * 256;
    for (int i = blockIdx.x * 256 + threadIdx.x; i < E_HP; i += stride) {
        unsigned pos = atomicAdd(&cursor[dst[i]], 1u);
        sorted_all[pos] = src[i];
    }
}

// ---------------- rh CSR fill: per-bucket LDS count + scan + row_ptr + fill ----------------
__global__ __launch_bounds__(256) void fillB_kernel(const unsigned long long* __restrict__ ebuf,
                                                    const unsigned* __restrict__ bstart,
                                                    unsigned* __restrict__ row_ptr,
                                                    int* __restrict__ sorted_all)
{
    __shared__ unsigned hist[1 << BSHIFT];   // 8KB: counts -> absolute cursors
    __shared__ unsigned wsum[4];
    int c = blockIdx.x;
    int dbase = c << BSHIFT;
    for (int i = threadIdx.x; i < (1 << BSHIFT); i += 256) hist[i] = 0;
    __syncthreads();
    unsigned e0 = bstart[c], e1 = bstart[c + 1];
    for (unsigned e = e0 + threadIdx.x; e < e1; e += 256)
        atomicAdd(&hist[(unsigned)(ebuf[e] >> 32) - dbase], 1u);
    __syncthreads();
    int base8 = threadIdx.x * 8;
    unsigned loc[8], s = 0;
#pragma unroll
    for (int i = 0; i < 8; ++i) { loc[i] = s; s += hist[base8 + i]; }
    int lane = threadIdx.x & 63, wv = threadIdx.x >> 6;
    unsigned sc = s;
    for (int off = 1; off < 64; off <<= 1) {
        unsigned t = __shfl_up(sc, off, 64);
        if (lane >= off) sc += t;
    }
    if (lane == 63) wsum[wv] = sc;
    __syncthreads();
    unsigned woff = 0;
    for (int w = 0; w < wv; ++w) woff += wsum[w];
    unsigned tbase = E_HP + e0 + woff + sc - s;
#pragma unroll
    for (int i = 0; i < 8; ++i) {
        int dd = dbase + base8 + i;
        unsigned p = tbase + loc[i];
        if (dd < N_SOTU) row_ptr[N_TAXON + dd] = p;
        hist[base8 + i] = p;
    }
    __syncthreads();
    for (unsigned e = e0 + threadIdx.x; e < e1; e += 256) {
        unsigned long long v = ebuf[e];
        unsigned pos = atomicAdd(&hist[(unsigned)(v >> 32) - dbase], 1u);
        sorted_all[pos] = (int)(unsigned)v;
    }
}

// ---------------- all weights: transpose + bf16 + XOR-swizzle ----------------
__global__ __launch_bounds__(256) void wprep_all_kernel(
    const float* __restrict__ W1l, const float* __restrict__ W1r,
    const float* __restrict__ W2l, const float* __restrict__ W2r,
    const float* __restrict__ W3l, const float* __restrict__ W3r,
    const float* __restrict__ Wlin, unsigned short* __restrict__ wtbase)
{
    int e = blockIdx.x * 256 + threadIdx.x;
    if (e >= 6 * 16384 + 8192) return;
    const float* srcs[7] = { W1l, W1r, W2l, W2r, W3l, W3r, Wlin };
    int m = e >> 14;
    int local = (m < 6) ? (e & 16383) : (e - 98304);
    int N = (m < 6) ? 128 : 64;
    int k = local / N, col = local - k * N;
    unsigned short* dst = wtbase + ((m < 6) ? m * 16384 : 98304);
    dst[(col * 128 + k) ^ ((col & 7) << 3)] = f2bf(srcs[m][local]);
}

// ---------------- hp mean gather from f32 x_taxon (XCD-swizzled) ----------------
__global__ __launch_bounds__(256) void aggMeanHp_kernel(
    const float* __restrict__ x, const unsigned* __restrict__ rp,
    const int* __restrict__ nbr, unsigned* __restrict__ outm)
{
    int wave = threadIdx.x >> 6, lane = threadIdx.x & 63;
    int bid = (blockIdx.x & 7) * 3125 + (blockIdx.x >> 3);   // grid = 25000
    int r = bid * 4 + wave;
    unsigned beg = rp[r], end = rp[r + 1];
    float a0 = 0.f, a1 = 0.f;
    unsigned u = beg;
    for (; u + 2 <= end; u += 2) {
        float2 A = ((const float2*)x)[(size_t)nbr[u] * 64 + lane];
        float2 B = ((const float2*)x)[(size_t)nbr[u + 1] * 64 + lane];
        a0 += A.x + B.x; a1 += A.y + B.y;
    }
    if (u < end) {
        float2 A = ((const float2*)x)[(size_t)nbr[u] * 64 + lane];
        a0 += A.x; a1 += A.y;
    }
    unsigned c = end - beg;
    float inv = 1.f / (float)(c ? c : 1u);
    outm[(size_t)r * 64 + lane] = packbf(a0 * inv, a1 * inv);
}

// ---------------- taxon_h GEMM (1024 thr, 16 waves, 256 rows/block) -> full X2 rows ----------------
__global__ __launch_bounds__(1024) void gemmTh_kernel(
    const unsigned* __restrict__ A1 /*meanX_hp*/, const float* __restrict__ X /*x_taxon f32*/,
    const unsigned short* __restrict__ WtA, const unsigned short* __restrict__ WtB,
    const float* __restrict__ bias, unsigned* __restrict__ X2, int M)
{
    __shared__ char sW[65536];
    {
        int tid = threadIdx.x;
        ((i32x4*)sW)[tid]        = ((const i32x4*)WtA)[tid];
        ((i32x4*)sW)[tid + 1024] = ((const i32x4*)WtA)[tid + 1024];
        ((i32x4*)sW)[tid + 2048] = ((const i32x4*)WtB)[tid];
        ((i32x4*)sW)[tid + 3072] = ((const i32x4*)WtB)[tid + 1024];
    }
    __syncthreads();

    int wave = threadIdx.x >> 6, lane = threadIdx.x & 63;
    int ln = lane & 15, g = lane >> 4;
    int row = blockIdx.x * 256 + wave * 16 + ln;
    int rl = row < M ? row : M - 1;
    int swz = (ln & 7) << 4;

    f32x4 acc[8];
#pragma unroll
    for (int cf = 0; cf < 8; ++cf) acc[cf] = ((const f32x4*)bias)[cf * 4 + g];

    const i32x4* a1r = (const i32x4*)(A1 + (size_t)rl * 64);
    const f32x4* xr = (const f32x4*)(X + (size_t)rl * 128);
    unsigned* orow = X2 + (size_t)row * 128;
    i32x4 xpk[4];
#pragma unroll
    for (int ks = 0; ks < 4; ++ks) {
        Frag mf; mf.i = a1r[ks * 4 + g];
        f32x4 fa = xr[ks * 8 + g * 2], fb = xr[ks * 8 + g * 2 + 1];
        Frag xf;
        i32x4 t = { (int)packbf(fa.x, fa.y), (int)packbf(fa.z, fa.w),
                    (int)packbf(fb.x, fb.y), (int)packbf(fb.z, fb.w) };
        xf.i = t; xpk[ks] = t;
#pragma unroll
        for (int cf = 0; cf < 8; ++cf) {
            int off = (((cf * 16 + ln) << 8) + (ks << 6) + (g << 4)) ^ swz;
            Frag wa; wa.i = *(const i32x4*)(sW + off);
            Frag wb; wb.i = *(const i32x4*)(sW + 32768 + off);
            acc[cf] = __builtin_amdgcn_mfma_f32_16x16x32_bf16(wa.v, mf.v, acc[cf], 0, 0, 0);
            acc[cf] = __builtin_amdgcn_mfma_f32_16x16x32_bf16(wb.v, xf.v, acc[cf], 0, 0, 0);
        }
    }

    if (row < M) {
#pragma unroll
        for (int ks = 0; ks < 4; ++ks) {
            int p0 = 16 * ks + 4 * g;
            orow[(p0 + 0) * 2] = (unsigned)xpk[ks][0];
            orow[(p0 + 1) * 2] = (unsigned)xpk[ks][1];
            orow[(p0 + 2) * 2] = (unsigned)xpk[ks][2];
            orow[(p0 + 3) * 2] = (unsigned)xpk[ks][3];
        }
#pragma unroll
        for (int cf = 0; cf < 8; ++cf) {
            int p = cf * 8 + g * 2;
            orow[p * 2 + 1]       = packbf(fmaxf(acc[cf][0], 0.f), fmaxf(acc[cf][1], 0.f));
            orow[(p + 1) * 2 + 1] = packbf(fmaxf(acc[cf][2], 0.f), fmaxf(acc[cf][3], 0.f));
        }
    }
}

// ---------------- merged rh gather: meanXrh + meanH in ONE walk (XCD-swizzled) ----------------
__global__ __launch_bounds__(256) void aggMean2_kernel(
    const unsigned* __restrict__ X2, const unsigned* __restrict__ rp,
    const int* __restrict__ nbr,
    unsigned* __restrict__ meanXrh, unsigned* __restrict__ meanH)
{
    int wave = threadIdx.x >> 6, lane = threadIdx.x & 63;
    int bid = (blockIdx.x & 7) * 6250 + (blockIdx.x >> 3);   // grid = 50000
    int r = bid * 4 + wave;
    unsigned beg = rp[r], end = rp[r + 1];
    float a0 = 0.f, a1 = 0.f, a2 = 0.f, a3 = 0.f;
    unsigned u = beg;
    for (; u + 2 <= end; u += 2) {
        int j0 = nbr[u], j1 = nbr[u + 1];
        u32x2 A = *(const u32x2*)(X2 + (size_t)j0 * 128 + lane * 2);
        u32x2 B = *(const u32x2*)(X2 + (size_t)j1 * 128 + lane * 2);
        a0 += bflo(A.x) + bflo(B.x); a1 += bfhi(A.x) + bfhi(B.x);
        a2 += bflo(A.y) + bflo(B.y); a3 += bfhi(A.y) + bfhi(B.y);
    }
    if (u < end) {
        u32x2 A = *(const u32x2*)(X2 + (size_t)nbr[u] * 128 + lane * 2);
        a0 += bflo(A.x); a1 += bfhi(A.x); a2 += bflo(A.y); a3 += bfhi(A.y);
    }
    unsigned c = end - beg;
    float inv = 1.f / (float)(c ? c : 1u);
    meanXrh[(size_t)r * 64 + lane] = packbf(a0 * inv, a1 * inv);
    meanH[(size_t)r * 64 + lane]   = packbf(a2 * inv, a3 * inv);
}

// ---------------- megaTail: sotu_h (LDS tiles) -> h2 (in-place tiles) -> out ----------------
// 1024 threads, 16 waves, 256 rows/block; 128KB LDS (64 sW + 64 tiles); all phases uniform
__global__ __launch_bounds__(1024) void megaTail_kernel(
    const unsigned* __restrict__ meanXrh, const float* __restrict__ xs,
    const unsigned* __restrict__ meanH,
    const unsigned short* __restrict__ Wt2l, const unsigned short* __restrict__ Wt2r,
    const unsigned short* __restrict__ Wt3l, const unsigned short* __restrict__ Wt3r,
    const unsigned short* __restrict__ Wtlin,
    const float* __restrict__ b2, const float* __restrict__ b3,
    const float* __restrict__ blin, float* __restrict__ out, int M)
{
    __shared__ char sW[65536];
    __shared__ unsigned tiles[16 * 1024];   // per-wave 16x64-pair tile, XOR-swizzled
    int tid = threadIdx.x;
    int wave = tid >> 6, lane = tid & 63;
    int ln = lane & 15, g = lane >> 4;
    int row = blockIdx.x * 256 + wave * 16 + ln;
    int rl = row < M ? row : M - 1;
    int swzW = (ln & 7) << 4;
    int swz = (ln & 7) << 2;
    unsigned* tile = tiles + wave * 1024;

    // preload W3 + Wlin into registers (issued early; consumed after barriers)
    i32x4 w3pre[4], wlpre;
    w3pre[0] = ((const i32x4*)Wt3l)[tid];
    w3pre[1] = ((const i32x4*)Wt3l)[tid + 1024];
    w3pre[2] = ((const i32x4*)Wt3r)[tid];
    w3pre[3] = ((const i32x4*)Wt3r)[tid + 1024];
    wlpre    = ((const i32x4*)Wtlin)[tid];

    // stage W2l|W2r
    ((i32x4*)sW)[tid]        = ((const i32x4*)Wt2l)[tid];
    ((i32x4*)sW)[tid + 1024] = ((const i32x4*)Wt2l)[tid + 1024];
    ((i32x4*)sW)[tid + 2048] = ((const i32x4*)Wt2r)[tid];
    ((i32x4*)sW)[tid + 3072] = ((const i32x4*)Wt2r)[tid + 1024];
    __syncthreads();   // B1

    // ---- phase A: sotu_h = relu(meanXrh@W2l + x_sotu@W2r + b2) -> tile ----
    {
        f32x4 acc[8];
#pragma unroll
        for (int cf = 0; cf < 8; ++cf) acc[cf] = ((const f32x4*)b2)[cf * 4 + g];
        const i32x4* a1r = (const i32x4*)(meanXrh + (size_t)rl * 64);
        const f32x4* xr = (const f32x4*)(xs + (size_t)rl * 128);
#pragma unroll
        for (int ks = 0; ks < 4; ++ks) {
            Frag mf; mf.i = a1r[ks * 4 + g];
            f32x4 fa = xr[ks * 8 + g * 2], fb = xr[ks * 8 + g * 2 + 1];
            Frag xf;
            i32x4 t = { (int)packbf(fa.x, fa.y), (int)packbf(fa.z, fa.w),
                        (int)packbf(fb.x, fb.y), (int)packbf(fb.z, fb.w) };
            xf.i = t;
#pragma unroll
            for (int cf = 0; cf < 8; ++cf) {
                int off = (((cf * 16 + ln) << 8) + (ks << 6) + (g << 4)) ^ swzW;
                Frag wa; wa.i = *(const i32x4*)(sW + off);
                Frag wb; wb.i = *(const i32x4*)(sW + 32768 + off);
                acc[cf] = __builtin_amdgcn_mfma_f32_16x16x32_bf16(wa.v, mf.v, acc[cf], 0, 0, 0);
                acc[cf] = __builtin_amdgcn_mfma_f32_16x16x32_bf16(wb.v, xf.v, acc[cf], 0, 0, 0);
            }
        }
#pragma unroll
        for (int cf = 0; cf < 8; ++cf) {
            u32x2 o;
            o.x = packbf(fmaxf(acc[cf][0], 0.f), fmaxf(acc[cf][1], 0.f));
            o.y = packbf(fmaxf(acc[cf][2], 0.f), fmaxf(acc[cf][3], 0.f));
            *(u32x2*)&tile[ln * 64 + ((cf * 8 + g * 2) ^ swz)] = o;
        }
    }

    // load meanH frags (overlaps with W3 restage)
    i32x4 mh[4];
    {
        const i32x4* hr = (const i32x4*)(meanH + (size_t)rl * 64);
#pragma unroll
        for (int ks = 0; ks < 4; ++ks) mh[ks] = hr[ks * 4 + g];
    }
    __syncthreads();   // B2: all W2 reads done
    ((i32x4*)sW)[tid]        = w3pre[0];
    ((i32x4*)sW)[tid + 1024] = w3pre[1];
    ((i32x4*)sW)[tid + 2048] = w3pre[2];
    ((i32x4*)sW)[tid + 3072] = w3pre[3];
    __syncthreads();   // B3

    // ---- phase B: h2 = relu(meanH@W3l + sotu_h@W3r + b3) -> tile (in place) ----
    {
        f32x4 acc2[8];
#pragma unroll
        for (int cf = 0; cf < 8; ++cf) acc2[cf] = ((const f32x4*)b3)[cf * 4 + g];
#pragma unroll
        for (int ks = 0; ks < 4; ++ks) {
            Frag mf; mf.i = mh[ks];
            Frag sf; sf.i = *(const i32x4*)&tile[ln * 64 + ((ks * 16 + g * 4) ^ swz)];
#pragma unroll
            for (int cf = 0; cf < 8; ++cf) {
                int off = (((cf * 16 + ln) << 8) + (ks << 6) + (g << 4)) ^ swzW;
                Frag wl; wl.i = *(const i32x4*)(sW + off);
                Frag wr; wr.i = *(const i32x4*)(sW + 32768 + off);
                acc2[cf] = __builtin_amdgcn_mfma_f32_16x16x32_bf16(wl.v, mf.v, acc2[cf], 0, 0, 0);
                acc2[cf] = __builtin_amdgcn_mfma_f32_16x16x32_bf16(wr.v, sf.v, acc2[cf], 0, 0, 0);
            }
        }
        // overwrite tile with h2 (wave-local; program-order DS ops make this safe)
#pragma unroll
        for (int cf = 0; cf < 8; ++cf) {
            u32x2 o;
            o.x = packbf(fmaxf(acc2[cf][0], 0.f), fmaxf(acc2[cf][1], 0.f));
            o.y = packbf(fmaxf(acc2[cf][2], 0.f), fmaxf(acc2[cf][3], 0.f));
            *(u32x2*)&tile[ln * 64 + ((cf * 8 + g * 2) ^ swz)] = o;
        }
    }
    __syncthreads();   // B4: all W3 reads done
    ((i32x4*)sW)[tid] = wlpre;   // Wlin image (16KB) at sW base
    __syncthreads();   // B5

    // ---- phase C: out = h2 @ Wlin + blin ----
    f32x4 aL[4];
#pragma unroll
    for (int cf = 0; cf < 4; ++cf) aL[cf] = ((const f32x4*)blin)[cf * 4 + g];
#pragma unroll
    for (int ks = 0; ks < 4; ++ks) {
        Frag hf; hf.i = *(const i32x4*)&tile[ln * 64 + ((ks * 16 + g * 4) ^ swz)];
#pragma unroll
        for (int cf = 0; cf < 4; ++cf) {
            int off = (((cf * 16 + ln) << 8) + (ks << 6) + (g << 4)) ^ swzW;
            Frag wf; wf.i = *(const i32x4*)(sW + off);
            aL[cf] = __builtin_amdgcn_mfma_f32_16x16x32_bf16(wf.v, hf.v, aL[cf], 0, 0, 0);
        }
    }
    if (row < M) {
        float* orow = out + (size_t)row * OUTC;
#pragma unroll
        for (int cf = 0; cf < 4; ++cf)
            *(f32x4*)(orow + cf * 16 + g * 4) = aL[cf];
    }
}

extern "C" void kernel_launch(void* const* d_in, const int* in_sizes, int n_in,
                              void* d_out, int out_size, void* d_ws, size_t ws_size,
                              hipStream_t stream)
{
    const float* x_taxon = (const float*)d_in[0];
    const float* x_sotu  = (const float*)d_in[1];
    const int* hp_src = (const int*)d_in[2];
    const int* hp_dst = (const int*)d_in[3];
    const int* rh_src = (const int*)d_in[4];
    const int* rh_dst = (const int*)d_in[5];
    const float* W1l = (const float*)d_in[6];
    const float* W1r = (const float*)d_in[7];
    const float* b1  = (const float*)d_in[8];
    const float* W2l = (const float*)d_in[9];
    const float* W2r = (const float*)d_in[10];
    const float* b2  = (const float*)d_in[11];
    const float* W3l = (const float*)d_in[12];
    const float* W3r = (const float*)d_in[13];
    const float* b3  = (const float*)d_in[14];
    const float* Wlin = (const float*)d_in[15];
    const float* blin = (const float*)d_in[16];
    float* out = (float*)d_out;

    // ---- workspace layout (bytes), peak ~190.3 MB ----
    char* ws = (char*)d_ws;
    unsigned* X2      = (unsigned*)(ws);                  // [100K][128] xt|taxon_h interleaved
    unsigned* meanXrh = (unsigned*)(ws + 51200000);       // [200K][64]; ebuf overlays (dead first)
    unsigned* meanH   = (unsigned*)(ws + 102400000);      // [200K][64]
    unsigned* meanX_hp= (unsigned*)(ws + 153600000);      // [100K][64]
    unsigned long long* ebuf = (unsigned long long*)(ws + 51200000);  // 16MB, dead before aggMean2
    int*      sorted_all = (int*)(ws + 179200000);        // 8.8MB
    unsigned* row_ptr = (unsigned*)(ws + 188000000);      // [300001]
    unsigned* cursor  = (unsigned*)(ws + 189200128);      // [100000]
    unsigned* cnt_t   = (unsigned*)(ws + 189600128);      // [100000]
    unsigned* bcnt    = (unsigned*)(ws + 190000128);      // [128]
    unsigned* bcursor = (unsigned*)(ws + 190000640);      // [128]
    unsigned* bstart  = (unsigned*)(ws + 190001152);      // [128]
    unsigned* bsum    = (unsigned*)(ws + 190001664);      // [2048]
    unsigned short* wtbase = (unsigned short*)(ws + 190009856);
    unsigned short* Wt1l = wtbase;
    unsigned short* Wt1r = wtbase + 16384;
    unsigned short* Wt2l = wtbase + 32768;
    unsigned short* Wt2r = wtbase + 49152;
    unsigned short* Wt3l = wtbase + 65536;
    unsigned short* Wt3r = wtbase + 81920;
    unsigned short* Wtlin = wtbase + 98304;

    // zero cnt_t [100000] + bcnt [128] (contiguous)
    hipMemsetAsync(cnt_t, 0, 100000 * 4 + 512, stream);

    // ---- CSR build ----
    countAll_kernel<<<256, 256, 0, stream>>>(hp_dst, rh_dst, cnt_t, bcnt);
    scan98_kernel<<<1, 128, 0, stream>>>(bcnt, bcursor, bstart, row_ptr);
    partition_kernel<<<(E_RH + 4095) / 4096, 256, 0, stream>>>(rh_src, rh_dst, bcursor, ebuf, E_RH);
    {
        int nb = (N_TAXON + 255) / 256;   // 391
        scanA_kernel<<<nb, 256, 0, stream>>>(cnt_t, bsum, N_TAXON);
        scanB_kernel<<<1, 1024, 0, stream>>>(bsum, nb, row_ptr + N_TAXON);
        scanC_kernel<<<nb, 256, 0, stream>>>(cnt_t, bsum, row_ptr, cursor, N_TAXON);
    }
    fill_hp_kernel<<<782, 256, 0, stream>>>(hp_src, hp_dst, cursor, sorted_all);
    fillB_kernel<<<NBUCK, 256, 0, stream>>>(ebuf, bstart, row_ptr, sorted_all);

    // ---- weight prep ----
    wprep_all_kernel<<<(6 * 16384 + 8192 + 255) / 256, 256, 0, stream>>>(
        W1l, W1r, W2l, W2r, W3l, W3r, Wlin, wtbase);

    // ---- meanX_hp over hp CSR (f32 source) ----
    aggMeanHp_kernel<<<N_TAXON / 4, 256, 0, stream>>>(x_taxon, row_ptr, sorted_all, meanX_hp);

    // ---- taxon_h GEMM -> full X2 rows (1024-thread blocks) ----
    gemmTh_kernel<<<(N_TAXON + 255) / 256, 1024, 0, stream>>>(
        meanX_hp, x_taxon, Wt1l, Wt1r, b1, X2, N_TAXON);

    // ---- merged rh gather: meanXrh + meanH in one walk ----
    aggMean2_kernel<<<N_SOTU / 4, 256, 0, stream>>>(
        X2, row_ptr + N_TAXON, sorted_all, meanXrh, meanH);

    // ---- megaTail: sotu_h -> h2 (LDS) -> out, one kernel ----
    megaTail_kernel<<<(N_SOTU + 255) / 256, 1024, 0, stream>>>(
        meanXrh, x_sotu, meanH, Wt2l, Wt2r, Wt3l, Wt3r, Wtlin, b2, b3, blin, out, N_SOTU);
}

// Round 15
// 445.927 us; speedup vs baseline: 1.1924x; 1.0287x over previous
//
#include <hip/hip_runtime.h>
#include <hip/hip_bf16.h>

#define D 128
#define N_TAXON 100000
#define N_SOTU 200000
#define N_ALL 300000
#define E_HP 200000
#define E_RH 2000000
#define E_ALL 2200000
#define OUTC 64
#define NBUCK 147     // ceil(300000 / 2048)
#define BSHIFT 11

typedef __hip_bfloat16 bf16;
typedef __bf16 bf16v8 __attribute__((ext_vector_type(8)));
typedef float f32x4 __attribute__((ext_vector_type(4)));
typedef int i32x4 __attribute__((ext_vector_type(4)));
typedef unsigned u32x2 __attribute__((ext_vector_type(2)));

union Frag { i32x4 i; bf16v8 v; };

__device__ __forceinline__ float bflo(unsigned u) { return __uint_as_float(u << 16); }
__device__ __forceinline__ float bfhi(unsigned u) { return __uint_as_float(u & 0xffff0000u); }

__device__ __forceinline__ unsigned short f2bf(float x) {
    unsigned u = __float_as_uint(x);
    unsigned r = (u + 0x7fffu + ((u >> 16) & 1u)) >> 16;   // round-to-nearest-even
    return (unsigned short)r;
}
__device__ __forceinline__ unsigned packbf(float a, float b) {
    return (unsigned)f2bf(a) | ((unsigned)f2bf(b) << 16);
}

// ---------------- unified bucket histogram over hp + rh ----------------
__global__ __launch_bounds__(256) void countAll_kernel(const int* __restrict__ hp_dst,
                                                       const int* __restrict__ rh_dst,
                                                       unsigned* __restrict__ bcnt)
{
    __shared__ unsigned hist[NBUCK];
    for (int i = threadIdx.x; i < NBUCK; i += 256) hist[i] = 0;
    __syncthreads();
    int stride = gridDim.x * 256;
    for (int e = blockIdx.x * 256 + threadIdx.x; e < E_HP; e += stride)
        atomicAdd(&hist[hp_dst[e] >> BSHIFT], 1u);
    for (int e = blockIdx.x * 256 + threadIdx.x; e < E_RH; e += stride)
        atomicAdd(&hist[(N_TAXON + rh_dst[e]) >> BSHIFT], 1u);
    __syncthreads();
    for (int i = threadIdx.x; i < NBUCK; i += 256) atomicAdd(&bcnt[i], hist[i]);
}

// ---------------- bucket prefix (+ final row_ptr sentinel) ----------------
__global__ __launch_bounds__(256) void scanB147_kernel(const unsigned* __restrict__ bcnt,
                                                       unsigned* __restrict__ bcursor,
                                                       unsigned* __restrict__ bstart,
                                                       unsigned* __restrict__ row_ptr)
{
    if (threadIdx.x == 0) {
        unsigned acc = 0;
        for (int b = 0; b < NBUCK; ++b) {
            unsigned t = bcnt[b];
            bcursor[b] = acc; bstart[b] = acc; acc += t;
        }
        bstart[NBUCK] = acc;
        row_ptr[N_ALL] = E_ALL;   // sentinel
    }
}

// ---------------- partition all edges into global-dst buckets ----------------
__global__ __launch_bounds__(256) void partition_kernel(
    const int* __restrict__ hp_src, const int* __restrict__ hp_dst,
    const int* __restrict__ rh_src, const int* __restrict__ rh_dst,
    unsigned* __restrict__ bcursor, unsigned long long* __restrict__ ebuf)
{
    __shared__ unsigned hist[NBUCK];
    __shared__ unsigned lcur[NBUCK];
    int base = blockIdx.x * 4096;
    for (int i = threadIdx.x; i < NBUCK; i += 256) hist[i] = 0;
    __syncthreads();
    int s[16], d[16];
#pragma unroll
    for (int k = 0; k < 16; ++k) {
        int e = base + k * 256 + threadIdx.x;
        if (e < E_HP) {
            s[k] = hp_src[e]; d[k] = hp_dst[e];
            atomicAdd(&hist[d[k] >> BSHIFT], 1u);
        } else if (e < E_ALL) {
            s[k] = rh_src[e - E_HP]; d[k] = N_TAXON + rh_dst[e - E_HP];
            atomicAdd(&hist[d[k] >> BSHIFT], 1u);
        } else d[k] = -1;
    }
    __syncthreads();
    for (int i = threadIdx.x; i < NBUCK; i += 256)
        lcur[i] = atomicAdd(&bcursor[i], hist[i]);
    __syncthreads();
#pragma unroll
    for (int k = 0; k < 16; ++k) {
        if (d[k] >= 0) {
            unsigned slot = atomicAdd(&lcur[d[k] >> BSHIFT], 1u);
            ebuf[slot] = ((unsigned long long)(unsigned)d[k] << 32) | (unsigned)s[k];
        }
    }
}

// ---------------- per-bucket: LDS count + scan -> row_ptr + dense fill ----------------
__global__ __launch_bounds__(256) void fillB_kernel(const unsigned long long* __restrict__ ebuf,
                                                    const unsigned* __restrict__ bstart,
                                                    unsigned* __restrict__ row_ptr,
                                                    int* __restrict__ sorted_all)
{
    __shared__ unsigned hist[1 << BSHIFT];   // 8KB: counts -> absolute cursors
    __shared__ unsigned wsum[4];
    int c = blockIdx.x;
    int dbase = c << BSHIFT;
    for (int i = threadIdx.x; i < (1 << BSHIFT); i += 256) hist[i] = 0;
    __syncthreads();
    unsigned e0 = bstart[c], e1 = bstart[c + 1];
    for (unsigned e = e0 + threadIdx.x; e < e1; e += 256)
        atomicAdd(&hist[(unsigned)(ebuf[e] >> 32) - dbase], 1u);
    __syncthreads();
    int base8 = threadIdx.x * 8;
    unsigned loc[8], s = 0;
#pragma unroll
    for (int i = 0; i < 8; ++i) { loc[i] = s; s += hist[base8 + i]; }
    int lane = threadIdx.x & 63, wv = threadIdx.x >> 6;
    unsigned sc = s;
    for (int off = 1; off < 64; off <<= 1) {
        unsigned t = __shfl_up(sc, off, 64);
        if (lane >= off) sc += t;
    }
    if (lane == 63) wsum[wv] = sc;
    __syncthreads();
    unsigned woff = 0;
    for (int w = 0; w < wv; ++w) woff += wsum[w];
    unsigned tbase = e0 + woff + sc - s;   // absolute exclusive prefix in sorted_all
#pragma unroll
    for (int i = 0; i < 8; ++i) {
        int dd = dbase + base8 + i;
        unsigned p = tbase + loc[i];
        if (dd < N_ALL) row_ptr[dd] = p;
        hist[base8 + i] = p;               // becomes the fill cursor
    }
    __syncthreads();
    for (unsigned e = e0 + threadIdx.x; e < e1; e += 256) {
        unsigned long long v = ebuf[e];
        unsigned pos = atomicAdd(&hist[(unsigned)(v >> 32) - dbase], 1u);
        sorted_all[pos] = (int)(unsigned)v;
    }
}

// ---------------- all weights: transpose + bf16 + XOR-swizzle ----------------
__global__ __launch_bounds__(256) void wprep_all_kernel(
    const float* __restrict__ W1l, const float* __restrict__ W1r,
    const float* __restrict__ W2l, const float* __restrict__ W2r,
    const float* __restrict__ W3l, const float* __restrict__ W3r,
    const float* __restrict__ Wlin, unsigned short* __restrict__ wtbase)
{
    int e = blockIdx.x * 256 + threadIdx.x;
    if (e >= 6 * 16384 + 8192) return;
    const float* srcs[7] = { W1l, W1r, W2l, W2r, W3l, W3r, Wlin };
    int m = e >> 14;
    int local = (m < 6) ? (e & 16383) : (e - 98304);
    int N = (m < 6) ? 128 : 64;
    int k = local / N, col = local - k * N;
    unsigned short* dst = wtbase + ((m < 6) ? m * 16384 : 98304);
    dst[(col * 128 + k) ^ ((col & 7) << 3)] = f2bf(srcs[m][local]);
}

// ---------------- gemmTh2: fused hp-mean gather + dual GEMM -> full X2 rows ----------------
// 1024 threads, 16 waves, 256 rows/block; gather deg~2 per row (cheap, wave-local)
__global__ __launch_bounds__(1024) void gemmTh2_kernel(
    const float* __restrict__ X /*x_taxon f32*/,
    const unsigned* __restrict__ rp, const int* __restrict__ nbr,
    const unsigned short* __restrict__ WtA, const unsigned short* __restrict__ WtB,
    const float* __restrict__ bias, unsigned* __restrict__ X2, int M)
{
    __shared__ char sW[65536];
    __shared__ unsigned tiles[16 * 1024];
    int tid = threadIdx.x;
    ((i32x4*)sW)[tid]        = ((const i32x4*)WtA)[tid];
    ((i32x4*)sW)[tid + 1024] = ((const i32x4*)WtA)[tid + 1024];
    ((i32x4*)sW)[tid + 2048] = ((const i32x4*)WtB)[tid];
    ((i32x4*)sW)[tid + 3072] = ((const i32x4*)WtB)[tid + 1024];

    int wave = tid >> 6, lane = tid & 63;
    int ln = lane & 15, g = lane >> 4;
    int rbase = blockIdx.x * 256 + wave * 16;
    unsigned* tile = tiles + wave * 1024;

    // ---- gather phase: mean of hp neighbors for the wave's 16 rows ----
    for (int i = 0; i < 16; ++i) {
        int r = rbase + i;
        float a0 = 0.f, a1 = 0.f;
        if (r < M) {
            unsigned beg = rp[r], end = rp[r + 1];
            unsigned u = beg;
            for (; u + 2 <= end; u += 2) {
                float2 A = ((const float2*)X)[(size_t)nbr[u] * 64 + lane];
                float2 B = ((const float2*)X)[(size_t)nbr[u + 1] * 64 + lane];
                a0 += A.x + B.x; a1 += A.y + B.y;
            }
            if (u < end) {
                float2 A = ((const float2*)X)[(size_t)nbr[u] * 64 + lane];
                a0 += A.x; a1 += A.y;
            }
            unsigned cdeg = end - beg;
            float inv = 1.f / (float)(cdeg ? cdeg : 1u);
            a0 *= inv; a1 *= inv;
        }
        tile[i * 64 + (lane ^ ((i & 7) << 2))] = packbf(a0, a1);
    }
    __syncthreads();

    // ---- GEMM phase ----
    int row = rbase + ln;
    int rl = row < M ? row : M - 1;
    int swzW = (ln & 7) << 4;
    int swz = (ln & 7) << 2;

    f32x4 acc[8];
#pragma unroll
    for (int cf = 0; cf < 8; ++cf) acc[cf] = ((const f32x4*)bias)[cf * 4 + g];

    const f32x4* xr = (const f32x4*)(X + (size_t)rl * 128);
    unsigned* orow = X2 + (size_t)row * 128;
    i32x4 xpk[4];
#pragma unroll
    for (int ks = 0; ks < 4; ++ks) {
        Frag mf; mf.i = *(const i32x4*)&tile[ln * 64 + ((ks * 16 + g * 4) ^ swz)];
        f32x4 fa = xr[ks * 8 + g * 2], fb = xr[ks * 8 + g * 2 + 1];
        Frag xf;
        i32x4 t = { (int)packbf(fa.x, fa.y), (int)packbf(fa.z, fa.w),
                    (int)packbf(fb.x, fb.y), (int)packbf(fb.z, fb.w) };
        xf.i = t; xpk[ks] = t;
#pragma unroll
        for (int cf = 0; cf < 8; ++cf) {
            int off = (((cf * 16 + ln) << 8) + (ks << 6) + (g << 4)) ^ swzW;
            Frag wa; wa.i = *(const i32x4*)(sW + off);
            Frag wb; wb.i = *(const i32x4*)(sW + 32768 + off);
            acc[cf] = __builtin_amdgcn_mfma_f32_16x16x32_bf16(wa.v, mf.v, acc[cf], 0, 0, 0);
            acc[cf] = __builtin_amdgcn_mfma_f32_16x16x32_bf16(wb.v, xf.v, acc[cf], 0, 0, 0);
        }
    }

    if (row < M) {
#pragma unroll
        for (int ks = 0; ks < 4; ++ks) {
            int p0 = 16 * ks + 4 * g;
            orow[(p0 + 0) * 2] = (unsigned)xpk[ks][0];
            orow[(p0 + 1) * 2] = (unsigned)xpk[ks][1];
            orow[(p0 + 2) * 2] = (unsigned)xpk[ks][2];
            orow[(p0 + 3) * 2] = (unsigned)xpk[ks][3];
        }
#pragma unroll
        for (int cf = 0; cf < 8; ++cf) {
            int p = cf * 8 + g * 2;
            orow[p * 2 + 1]       = packbf(fmaxf(acc[cf][0], 0.f), fmaxf(acc[cf][1], 0.f));
            orow[(p + 1) * 2 + 1] = packbf(fmaxf(acc[cf][2], 0.f), fmaxf(acc[cf][3], 0.f));
        }
    }
}

// ---------------- merged rh gather: meanXrh + meanH in ONE walk (XCD-swizzled) ----------------
__global__ __launch_bounds__(256) void aggMean2_kernel(
    const unsigned* __restrict__ X2, const unsigned* __restrict__ rp,
    const int* __restrict__ nbr,
    unsigned* __restrict__ meanXrh, unsigned* __restrict__ meanH)
{
    int wave = threadIdx.x >> 6, lane = threadIdx.x & 63;
    int bid = (blockIdx.x & 7) * 6250 + (blockIdx.x >> 3);   // grid = 50000
    int r = bid * 4 + wave;
    unsigned beg = rp[r], end = rp[r + 1];
    float a0 = 0.f, a1 = 0.f, a2 = 0.f, a3 = 0.f;
    unsigned u = beg;
    for (; u + 2 <= end; u += 2) {
        int j0 = nbr[u], j1 = nbr[u + 1];
        u32x2 A = *(const u32x2*)(X2 + (size_t)j0 * 128 + lane * 2);
        u32x2 B = *(const u32x2*)(X2 + (size_t)j1 * 128 + lane * 2);
        a0 += bflo(A.x) + bflo(B.x); a1 += bfhi(A.x) + bfhi(B.x);
        a2 += bflo(A.y) + bflo(B.y); a3 += bfhi(A.y) + bfhi(B.y);
    }
    if (u < end) {
        u32x2 A = *(const u32x2*)(X2 + (size_t)nbr[u] * 128 + lane * 2);
        a0 += bflo(A.x); a1 += bfhi(A.x); a2 += bflo(A.y); a3 += bfhi(A.y);
    }
    unsigned c = end - beg;
    float inv = 1.f / (float)(c ? c : 1u);
    meanXrh[(size_t)r * 64 + lane] = packbf(a0 * inv, a1 * inv);
    meanH[(size_t)r * 64 + lane]   = packbf(a2 * inv, a3 * inv);
}

// ---------------- megaTail: sotu_h (LDS tiles) -> h2 (in-place) -> out ----------------
__global__ __launch_bounds__(1024) void megaTail_kernel(
    const unsigned* __restrict__ meanXrh, const float* __restrict__ xs,
    const unsigned* __restrict__ meanH,
    const unsigned short* __restrict__ Wt2l, const unsigned short* __restrict__ Wt2r,
    const unsigned short* __restrict__ Wt3l, const unsigned short* __restrict__ Wt3r,
    const unsigned short* __restrict__ Wtlin,
    const float* __restrict__ b2, const float* __restrict__ b3,
    const float* __restrict__ blin, float* __restrict__ out, int M)
{
    __shared__ char sW[65536];
    __shared__ unsigned tiles[16 * 1024];
    int tid = threadIdx.x;
    int wave = tid >> 6, lane = tid & 63;
    int ln = lane & 15, g = lane >> 4;
    int row = blockIdx.x * 256 + wave * 16 + ln;
    int rl = row < M ? row : M - 1;
    int swzW = (ln & 7) << 4;
    int swz = (ln & 7) << 2;
    unsigned* tile = tiles + wave * 1024;

    i32x4 w3pre[4], wlpre;
    w3pre[0] = ((const i32x4*)Wt3l)[tid];
    w3pre[1] = ((const i32x4*)Wt3l)[tid + 1024];
    w3pre[2] = ((const i32x4*)Wt3r)[tid];
    w3pre[3] = ((const i32x4*)Wt3r)[tid + 1024];
    wlpre    = ((const i32x4*)Wtlin)[tid];

    ((i32x4*)sW)[tid]        = ((const i32x4*)Wt2l)[tid];
    ((i32x4*)sW)[tid + 1024] = ((const i32x4*)Wt2l)[tid + 1024];
    ((i32x4*)sW)[tid + 2048] = ((const i32x4*)Wt2r)[tid];
    ((i32x4*)sW)[tid + 3072] = ((const i32x4*)Wt2r)[tid + 1024];
    __syncthreads();   // B1

    // phase A: sotu_h = relu(meanXrh@W2l + x_sotu@W2r + b2) -> tile
    {
        f32x4 acc[8];
#pragma unroll
        for (int cf = 0; cf < 8; ++cf) acc[cf] = ((const f32x4*)b2)[cf * 4 + g];
        const i32x4* a1r = (const i32x4*)(meanXrh + (size_t)rl * 64);
        const f32x4* xr = (const f32x4*)(xs + (size_t)rl * 128);
#pragma unroll
        for (int ks = 0; ks < 4; ++ks) {
            Frag mf; mf.i = a1r[ks * 4 + g];
            f32x4 fa = xr[ks * 8 + g * 2], fb = xr[ks * 8 + g * 2 + 1];
            Frag xf;
            i32x4 t = { (int)packbf(fa.x, fa.y), (int)packbf(fa.z, fa.w),
                        (int)packbf(fb.x, fb.y), (int)packbf(fb.z, fb.w) };
            xf.i = t;
#pragma unroll
            for (int cf = 0; cf < 8; ++cf) {
                int off = (((cf * 16 + ln) << 8) + (ks << 6) + (g << 4)) ^ swzW;
                Frag wa; wa.i = *(const i32x4*)(sW + off);
                Frag wb; wb.i = *(const i32x4*)(sW + 32768 + off);
                acc[cf] = __builtin_amdgcn_mfma_f32_16x16x32_bf16(wa.v, mf.v, acc[cf], 0, 0, 0);
                acc[cf] = __builtin_amdgcn_mfma_f32_16x16x32_bf16(wb.v, xf.v, acc[cf], 0, 0, 0);
            }
        }
#pragma unroll
        for (int cf = 0; cf < 8; ++cf) {
            u32x2 o;
            o.x = packbf(fmaxf(acc[cf][0], 0.f), fmaxf(acc[cf][1], 0.f));
            o.y = packbf(fmaxf(acc[cf][2], 0.f), fmaxf(acc[cf][3], 0.f));
            *(u32x2*)&tile[ln * 64 + ((cf * 8 + g * 2) ^ swz)] = o;
        }
    }

    i32x4 mh[4];
    {
        const i32x4* hr = (const i32x4*)(meanH + (size_t)rl * 64);
#pragma unroll
        for (int ks = 0; ks < 4; ++ks) mh[ks] = hr[ks * 4 + g];
    }
    __syncthreads();   // B2
    ((i32x4*)sW)[tid]        = w3pre[0];
    ((i32x4*)sW)[tid + 1024] = w3pre[1];
    ((i32x4*)sW)[tid + 2048] = w3pre[2];
    ((i32x4*)sW)[tid + 3072] = w3pre[3];
    __syncthreads();   // B3

    // phase B: h2 = relu(meanH@W3l + sotu_h@W3r + b3) -> tile (in place)
    {
        f32x4 acc2[8];
#pragma unroll
        for (int cf = 0; cf < 8; ++cf) acc2[cf] = ((const f32x4*)b3)[cf * 4 + g];
#pragma unroll
        for (int ks = 0; ks < 4; ++ks) {
            Frag mf; mf.i = mh[ks];
            Frag sf; sf.i = *(const i32x4*)&tile[ln * 64 + ((ks * 16 + g * 4) ^ swz)];
#pragma unroll
            for (int cf = 0; cf < 8; ++cf) {
                int off = (((cf * 16 + ln) << 8) + (ks << 6) + (g << 4)) ^ swzW;
                Frag wl; wl.i = *(const i32x4*)(sW + off);
                Frag wr; wr.i = *(const i32x4*)(sW + 32768 + off);
                acc2[cf] = __builtin_amdgcn_mfma_f32_16x16x32_bf16(wl.v, mf.v, acc2[cf], 0, 0, 0);
                acc2[cf] = __builtin_amdgcn_mfma_f32_16x16x32_bf16(wr.v, sf.v, acc2[cf], 0, 0, 0);
            }
        }
#pragma unroll
        for (int cf = 0; cf < 8; ++cf) {
            u32x2 o;
            o.x = packbf(fmaxf(acc2[cf][0], 0.f), fmaxf(acc2[cf][1], 0.f));
            o.y = packbf(fmaxf(acc2[cf][2], 0.f), fmaxf(acc2[cf][3], 0.f));
            *(u32x2*)&tile[ln * 64 + ((cf * 8 + g * 2) ^ swz)] = o;
        }
    }
    __syncthreads();   // B4
    ((i32x4*)sW)[tid] = wlpre;
    __syncthreads();   // B5

    // phase C: out = h2 @ Wlin + blin
    f32x4 aL[4];
#pragma unroll
    for (int cf = 0; cf < 4; ++cf) aL[cf] = ((const f32x4*)blin)[cf * 4 + g];
#pragma unroll
    for (int ks = 0; ks < 4; ++ks) {
        Frag hf; hf.i = *(const i32x4*)&tile[ln * 64 + ((ks * 16 + g * 4) ^ swz)];
#pragma unroll
        for (int cf = 0; cf < 4; ++cf) {
            int off = (((cf * 16 + ln) << 8) + (ks << 6) + (g << 4)) ^ swzW;
            Frag wf; wf.i = *(const i32x4*)(sW + off);
            aL[cf] = __builtin_amdgcn_mfma_f32_16x16x32_bf16(wf.v, hf.v, aL[cf], 0, 0, 0);
        }
    }
    if (row < M) {
        float* orow = out + (size_t)row * OUTC;
#pragma unroll
        for (int cf = 0; cf < 4; ++cf)
            *(f32x4*)(orow + cf * 16 + g * 4) = aL[cf];
    }
}

extern "C" void kernel_launch(void* const* d_in, const int* in_sizes, int n_in,
                              void* d_out, int out_size, void* d_ws, size_t ws_size,
                              hipStream_t stream)
{
    const float* x_taxon = (const float*)d_in[0];
    const float* x_sotu  = (const float*)d_in[1];
    const int* hp_src = (const int*)d_in[2];
    const int* hp_dst = (const int*)d_in[3];
    const int* rh_src = (const int*)d_in[4];
    const int* rh_dst = (const int*)d_in[5];
    const float* W1l = (const float*)d_in[6];
    const float* W1r = (const float*)d_in[7];
    const float* b1  = (const float*)d_in[8];
    const float* W2l = (const float*)d_in[9];
    const float* W2r = (const float*)d_in[10];
    const float* b2  = (const float*)d_in[11];
    const float* W3l = (const float*)d_in[12];
    const float* W3r = (const float*)d_in[13];
    const float* b3  = (const float*)d_in[14];
    const float* Wlin = (const float*)d_in[15];
    const float* blin = (const float*)d_in[16];
    float* out = (float*)d_out;

    // ---- workspace layout (bytes), peak ~189.5 MB ----
    char* ws = (char*)d_ws;
    unsigned* X2      = (unsigned*)(ws);                  // [100K][128] xt|taxon_h interleaved
    unsigned* meanXrh = (unsigned*)(ws + 51200000);       // [200K][64]; ebuf overlays (dead first)
    unsigned* meanH   = (unsigned*)(ws + 102400000);      // [200K][64]
    unsigned long long* ebuf = (unsigned long long*)(ws + 51200000);  // 17.6MB, dead before aggMean2
    int*      sorted_all = (int*)(ws + 179200000);        // [E_ALL] 8.8MB
    unsigned* row_ptr = (unsigned*)(ws + 188000000);      // [300001]
    unsigned* bcnt    = (unsigned*)(ws + 189200128);      // [160]
    unsigned* bcursor = (unsigned*)(ws + 189200768);      // [160]
    unsigned* bstart  = (unsigned*)(ws + 189201408);      // [160]
    unsigned short* wtbase = (unsigned short*)(ws + 189202048);
    unsigned short* Wt1l = wtbase;
    unsigned short* Wt1r = wtbase + 16384;
    unsigned short* Wt2l = wtbase + 32768;
    unsigned short* Wt2r = wtbase + 49152;
    unsigned short* Wt3l = wtbase + 65536;
    unsigned short* Wt3r = wtbase + 81920;
    unsigned short* Wtlin = wtbase + 98304;

    // zero bcnt only
    hipMemsetAsync(bcnt, 0, 640, stream);

    // ---- unified CSR build (300K rows, 2.2M edges, 147 buckets) ----
    countAll_kernel<<<512, 256, 0, stream>>>(hp_dst, rh_dst, bcnt);
    scanB147_kernel<<<1, 256, 0, stream>>>(bcnt, bcursor, bstart, row_ptr);
    partition_kernel<<<(E_ALL + 4095) / 4096, 256, 0, stream>>>(
        hp_src, hp_dst, rh_src, rh_dst, bcursor, ebuf);
    fillB_kernel<<<NBUCK, 256, 0, stream>>>(ebuf, bstart, row_ptr, sorted_all);

    // ---- weight prep ----
    wprep_all_kernel<<<(6 * 16384 + 8192 + 255) / 256, 256, 0, stream>>>(
        W1l, W1r, W2l, W2r, W3l, W3r, Wlin, wtbase);

    // ---- fused hp-mean + taxon_h GEMM -> full X2 rows ----
    gemmTh2_kernel<<<(N_TAXON + 255) / 256, 1024, 0, stream>>>(
        x_taxon, row_ptr, sorted_all, Wt1l, Wt1r, b1, X2, N_TAXON);

    // ---- merged rh gather: meanXrh + meanH in one walk ----
    aggMean2_kernel<<<N_SOTU / 4, 256, 0, stream>>>(
        X2, row_ptr + N_TAXON, sorted_all, meanXrh, meanH);

    // ---- megaTail: sotu_h -> h2 (LDS) -> out ----
    megaTail_kernel<<<(N_SOTU + 255) / 256, 1024, 0, stream>>>(
        meanXrh, x_sotu, meanH, Wt2l, Wt2r, Wt3l, Wt3r, Wtlin, b2, b3, blin, out, N_SOTU);
}

// Round 16
// 445.007 us; speedup vs baseline: 1.1948x; 1.0021x over previous
//
#include <hip/hip_runtime.h>
#include <hip/hip_bf16.h>

#define D 128
#define N_TAXON 100000
#define N_SOTU 200000
#define N_ALL 300000
#define E_HP 200000
#define E_RH 2000000
#define E_ALL 2200000
#define OUTC 64
#define NBUCK 147     // ceil(300000 / 2048)
#define BSHIFT 11

typedef __hip_bfloat16 bf16;
typedef __bf16 bf16v8 __attribute__((ext_vector_type(8)));
typedef float f32x4 __attribute__((ext_vector_type(4)));
typedef int i32x4 __attribute__((ext_vector_type(4)));
typedef unsigned u32x2 __attribute__((ext_vector_type(2)));

union Frag { i32x4 i; bf16v8 v; };

__device__ __forceinline__ float bflo(unsigned u) { return __uint_as_float(u << 16); }
__device__ __forceinline__ float bfhi(unsigned u) { return __uint_as_float(u & 0xffff0000u); }

__device__ __forceinline__ unsigned short f2bf(float x) {
    unsigned u = __float_as_uint(x);
    unsigned r = (u + 0x7fffu + ((u >> 16) & 1u)) >> 16;   // round-to-nearest-even
    return (unsigned short)r;
}
__device__ __forceinline__ unsigned packbf(float a, float b) {
    return (unsigned)f2bf(a) | ((unsigned)f2bf(b) << 16);
}

// ---------------- unified bucket histogram over hp + rh ----------------
__global__ __launch_bounds__(256) void countAll_kernel(const int* __restrict__ hp_dst,
                                                       const int* __restrict__ rh_dst,
                                                       unsigned* __restrict__ bcnt)
{
    __shared__ unsigned hist[NBUCK];
    for (int i = threadIdx.x; i < NBUCK; i += 256) hist[i] = 0;
    __syncthreads();
    int stride = gridDim.x * 256;
    for (int e = blockIdx.x * 256 + threadIdx.x; e < E_HP; e += stride)
        atomicAdd(&hist[hp_dst[e] >> BSHIFT], 1u);
    for (int e = blockIdx.x * 256 + threadIdx.x; e < E_RH; e += stride)
        atomicAdd(&hist[(N_TAXON + rh_dst[e]) >> BSHIFT], 1u);
    __syncthreads();
    for (int i = threadIdx.x; i < NBUCK; i += 256) atomicAdd(&bcnt[i], hist[i]);
}

// ---------------- bucket prefix (+ final row_ptr sentinel) ----------------
__global__ __launch_bounds__(256) void scanB147_kernel(const unsigned* __restrict__ bcnt,
                                                       unsigned* __restrict__ bcursor,
                                                       unsigned* __restrict__ bstart,
                                                       unsigned* __restrict__ row_ptr)
{
    if (threadIdx.x == 0) {
        unsigned acc = 0;
        for (int b = 0; b < NBUCK; ++b) {
            unsigned t = bcnt[b];
            bcursor[b] = acc; bstart[b] = acc; acc += t;
        }
        bstart[NBUCK] = acc;
        row_ptr[N_ALL] = E_ALL;   // sentinel
    }
}

// ---------------- partition all edges into global-dst buckets ----------------
__global__ __launch_bounds__(256) void partition_kernel(
    const int* __restrict__ hp_src, const int* __restrict__ hp_dst,
    const int* __restrict__ rh_src, const int* __restrict__ rh_dst,
    unsigned* __restrict__ bcursor, unsigned long long* __restrict__ ebuf)
{
    __shared__ unsigned hist[NBUCK];
    __shared__ unsigned lcur[NBUCK];
    int base = blockIdx.x * 4096;
    for (int i = threadIdx.x; i < NBUCK; i += 256) hist[i] = 0;
    __syncthreads();
    int s[16], d[16];
#pragma unroll
    for (int k = 0; k < 16; ++k) {
        int e = base + k * 256 + threadIdx.x;
        if (e < E_HP) {
            s[k] = hp_src[e]; d[k] = hp_dst[e];
            atomicAdd(&hist[d[k] >> BSHIFT], 1u);
        } else if (e < E_ALL) {
            s[k] = rh_src[e - E_HP]; d[k] = N_TAXON + rh_dst[e - E_HP];
            atomicAdd(&hist[d[k] >> BSHIFT], 1u);
        } else d[k] = -1;
    }
    __syncthreads();
    for (int i = threadIdx.x; i < NBUCK; i += 256)
        lcur[i] = atomicAdd(&bcursor[i], hist[i]);
    __syncthreads();
#pragma unroll
    for (int k = 0; k < 16; ++k) {
        if (d[k] >= 0) {
            unsigned slot = atomicAdd(&lcur[d[k] >> BSHIFT], 1u);
            ebuf[slot] = ((unsigned long long)(unsigned)d[k] << 32) | (unsigned)s[k];
        }
    }
}

// ---------------- per-bucket: LDS count + scan -> row_ptr + dense fill ----------------
__global__ __launch_bounds__(256) void fillB_kernel(const unsigned long long* __restrict__ ebuf,
                                                    const unsigned* __restrict__ bstart,
                                                    unsigned* __restrict__ row_ptr,
                                                    int* __restrict__ sorted_all)
{
    __shared__ unsigned hist[1 << BSHIFT];   // 8KB: counts -> absolute cursors
    __shared__ unsigned wsum[4];
    int c = blockIdx.x;
    int dbase = c << BSHIFT;
    for (int i = threadIdx.x; i < (1 << BSHIFT); i += 256) hist[i] = 0;
    __syncthreads();
    unsigned e0 = bstart[c], e1 = bstart[c + 1];
    for (unsigned e = e0 + threadIdx.x; e < e1; e += 256)
        atomicAdd(&hist[(unsigned)(ebuf[e] >> 32) - dbase], 1u);
    __syncthreads();
    int base8 = threadIdx.x * 8;
    unsigned loc[8], s = 0;
#pragma unroll
    for (int i = 0; i < 8; ++i) { loc[i] = s; s += hist[base8 + i]; }
    int lane = threadIdx.x & 63, wv = threadIdx.x >> 6;
    unsigned sc = s;
    for (int off = 1; off < 64; off <<= 1) {
        unsigned t = __shfl_up(sc, off, 64);
        if (lane >= off) sc += t;
    }
    if (lane == 63) wsum[wv] = sc;
    __syncthreads();
    unsigned woff = 0;
    for (int w = 0; w < wv; ++w) woff += wsum[w];
    unsigned tbase = e0 + woff + sc - s;   // absolute exclusive prefix in sorted_all
#pragma unroll
    for (int i = 0; i < 8; ++i) {
        int dd = dbase + base8 + i;
        unsigned p = tbase + loc[i];
        if (dd < N_ALL) row_ptr[dd] = p;
        hist[base8 + i] = p;               // becomes the fill cursor
    }
    __syncthreads();
    for (unsigned e = e0 + threadIdx.x; e < e1; e += 256) {
        unsigned long long v = ebuf[e];
        unsigned pos = atomicAdd(&hist[(unsigned)(v >> 32) - dbase], 1u);
        sorted_all[pos] = (int)(unsigned)v;
    }
}

// ---------------- all weights: transpose + bf16 + XOR-swizzle ----------------
__global__ __launch_bounds__(256) void wprep_all_kernel(
    const float* __restrict__ W1l, const float* __restrict__ W1r,
    const float* __restrict__ W2l, const float* __restrict__ W2r,
    const float* __restrict__ W3l, const float* __restrict__ W3r,
    const float* __restrict__ Wlin, unsigned short* __restrict__ wtbase)
{
    int e = blockIdx.x * 256 + threadIdx.x;
    if (e >= 6 * 16384 + 8192) return;
    const float* srcs[7] = { W1l, W1r, W2l, W2r, W3l, W3r, Wlin };
    int m = e >> 14;
    int local = (m < 6) ? (e & 16383) : (e - 98304);
    int N = (m < 6) ? 128 : 64;
    int k = local / N, col = local - k * N;
    unsigned short* dst = wtbase + ((m < 6) ? m * 16384 : 98304);
    dst[(col * 128 + k) ^ ((col & 7) << 3)] = f2bf(srcs[m][local]);
}

// ---------------- gemmTh2: fused hp-mean gather + dual GEMM -> full X2 rows ----------------
// 1024 threads, 16 waves, 256 rows/block; gather deg~2 per row (cheap, wave-local)
__global__ __launch_bounds__(1024) void gemmTh2_kernel(
    const float* __restrict__ X /*x_taxon f32*/,
    const unsigned* __restrict__ rp, const int* __restrict__ nbr,
    const unsigned short* __restrict__ WtA, const unsigned short* __restrict__ WtB,
    const float* __restrict__ bias, unsigned* __restrict__ X2, int M)
{
    __shared__ char sW[65536];
    __shared__ unsigned tiles[16 * 1024];
    int tid = threadIdx.x;
    ((i32x4*)sW)[tid]        = ((const i32x4*)WtA)[tid];
    ((i32x4*)sW)[tid + 1024] = ((const i32x4*)WtA)[tid + 1024];
    ((i32x4*)sW)[tid + 2048] = ((const i32x4*)WtB)[tid];
    ((i32x4*)sW)[tid + 3072] = ((const i32x4*)WtB)[tid + 1024];

    int wave = tid >> 6, lane = tid & 63;
    int ln = lane & 15, g = lane >> 4;
    int rbase = blockIdx.x * 256 + wave * 16;
    unsigned* tile = tiles + wave * 1024;

    // ---- gather phase: mean of hp neighbors for the wave's 16 rows ----
    for (int i = 0; i < 16; ++i) {
        int r = rbase + i;
        float a0 = 0.f, a1 = 0.f;
        if (r < M) {
            unsigned beg = rp[r], end = rp[r + 1];
            unsigned u = beg;
            for (; u + 2 <= end; u += 2) {
                float2 A = ((const float2*)X)[(size_t)nbr[u] * 64 + lane];
                float2 B = ((const float2*)X)[(size_t)nbr[u + 1] * 64 + lane];
                a0 += A.x + B.x; a1 += A.y + B.y;
            }
            if (u < end) {
                float2 A = ((const float2*)X)[(size_t)nbr[u] * 64 + lane];
                a0 += A.x; a1 += A.y;
            }
            unsigned cdeg = end - beg;
            float inv = 1.f / (float)(cdeg ? cdeg : 1u);
            a0 *= inv; a1 *= inv;
        }
        tile[i * 64 + (lane ^ ((i & 7) << 2))] = packbf(a0, a1);
    }
    __syncthreads();

    // ---- GEMM phase ----
    int row = rbase + ln;
    int rl = row < M ? row : M - 1;
    int swzW = (ln & 7) << 4;
    int swz = (ln & 7) << 2;

    f32x4 acc[8];
#pragma unroll
    for (int cf = 0; cf < 8; ++cf) acc[cf] = ((const f32x4*)bias)[cf * 4 + g];

    const f32x4* xr = (const f32x4*)(X + (size_t)rl * 128);
    unsigned* orow = X2 + (size_t)row * 128;
    i32x4 xpk[4];
#pragma unroll
    for (int ks = 0; ks < 4; ++ks) {
        Frag mf; mf.i = *(const i32x4*)&tile[ln * 64 + ((ks * 16 + g * 4) ^ swz)];
        f32x4 fa = xr[ks * 8 + g * 2], fb = xr[ks * 8 + g * 2 + 1];
        Frag xf;
        i32x4 t = { (int)packbf(fa.x, fa.y), (int)packbf(fa.z, fa.w),
                    (int)packbf(fb.x, fb.y), (int)packbf(fb.z, fb.w) };
        xf.i = t; xpk[ks] = t;
#pragma unroll
        for (int cf = 0; cf < 8; ++cf) {
            int off = (((cf * 16 + ln) << 8) + (ks << 6) + (g << 4)) ^ swzW;
            Frag wa; wa.i = *(const i32x4*)(sW + off);
            Frag wb; wb.i = *(const i32x4*)(sW + 32768 + off);
            acc[cf] = __builtin_amdgcn_mfma_f32_16x16x32_bf16(wa.v, mf.v, acc[cf], 0, 0, 0);
            acc[cf] = __builtin_amdgcn_mfma_f32_16x16x32_bf16(wb.v, xf.v, acc[cf], 0, 0, 0);
        }
    }

    if (row < M) {
#pragma unroll
        for (int ks = 0; ks < 4; ++ks) {
            int p0 = 16 * ks + 4 * g;
            orow[(p0 + 0) * 2] = (unsigned)xpk[ks][0];
            orow[(p0 + 1) * 2] = (unsigned)xpk[ks][1];
            orow[(p0 + 2) * 2] = (unsigned)xpk[ks][2];
            orow[(p0 + 3) * 2] = (unsigned)xpk[ks][3];
        }
#pragma unroll
        for (int cf = 0; cf < 8; ++cf) {
            int p = cf * 8 + g * 2;
            orow[p * 2 + 1]       = packbf(fmaxf(acc[cf][0], 0.f), fmaxf(acc[cf][1], 0.f));
            orow[(p + 1) * 2 + 1] = packbf(fmaxf(acc[cf][2], 0.f), fmaxf(acc[cf][3], 0.f));
        }
    }
}

// ---------------- merged rh gather: meanXrh + meanH in ONE walk (XCD-swizzled) ----------------
__global__ __launch_bounds__(256) void aggMean2_kernel(
    const unsigned* __restrict__ X2, const unsigned* __restrict__ rp,
    const int* __restrict__ nbr,
    unsigned* __restrict__ meanXrh, unsigned* __restrict__ meanH)
{
    int wave = threadIdx.x >> 6, lane = threadIdx.x & 63;
    int bid = (blockIdx.x & 7) * 6250 + (blockIdx.x >> 3);   // grid = 50000
    int r = bid * 4 + wave;
    unsigned beg = rp[r], end = rp[r + 1];
    float a0 = 0.f, a1 = 0.f, a2 = 0.f, a3 = 0.f;
    unsigned u = beg;
    for (; u + 2 <= end; u += 2) {
        int j0 = nbr[u], j1 = nbr[u + 1];
        u32x2 A = *(const u32x2*)(X2 + (size_t)j0 * 128 + lane * 2);
        u32x2 B = *(const u32x2*)(X2 + (size_t)j1 * 128 + lane * 2);
        a0 += bflo(A.x) + bflo(B.x); a1 += bfhi(A.x) + bfhi(B.x);
        a2 += bflo(A.y) + bflo(B.y); a3 += bfhi(A.y) + bfhi(B.y);
    }
    if (u < end) {
        u32x2 A = *(const u32x2*)(X2 + (size_t)nbr[u] * 128 + lane * 2);
        a0 += bflo(A.x); a1 += bfhi(A.x); a2 += bflo(A.y); a3 += bfhi(A.y);
    }
    unsigned c = end - beg;
    float inv = 1.f / (float)(c ? c : 1u);
    meanXrh[(size_t)r * 64 + lane] = packbf(a0 * inv, a1 * inv);
    meanH[(size_t)r * 64 + lane]   = packbf(a2 * inv, a3 * inv);
}

// ---------------- megaTail: sotu_h (LDS tiles) -> h2 (in-place) -> out ----------------
__global__ __launch_bounds__(1024) void megaTail_kernel(
    const unsigned* __restrict__ meanXrh, const float* __restrict__ xs,
    const unsigned* __restrict__ meanH,
    const unsigned short* __restrict__ Wt2l, const unsigned short* __restrict__ Wt2r,
    const unsigned short* __restrict__ Wt3l, const unsigned short* __restrict__ Wt3r,
    const unsigned short* __restrict__ Wtlin,
    const float* __restrict__ b2, const float* __restrict__ b3,
    const float* __restrict__ blin, float* __restrict__ out, int M)
{
    __shared__ char sW[65536];
    __shared__ unsigned tiles[16 * 1024];
    int tid = threadIdx.x;
    int wave = tid >> 6, lane = tid & 63;
    int ln = lane & 15, g = lane >> 4;
    int row = blockIdx.x * 256 + wave * 16 + ln;
    int rl = row < M ? row : M - 1;
    int swzW = (ln & 7) << 4;
    int swz = (ln & 7) << 2;
    unsigned* tile = tiles + wave * 1024;

    i32x4 w3pre[4], wlpre;
    w3pre[0] = ((const i32x4*)Wt3l)[tid];
    w3pre[1] = ((const i32x4*)Wt3l)[tid + 1024];
    w3pre[2] = ((const i32x4*)Wt3r)[tid];
    w3pre[3] = ((const i32x4*)Wt3r)[tid + 1024];
    wlpre    = ((const i32x4*)Wtlin)[tid];

    ((i32x4*)sW)[tid]        = ((const i32x4*)Wt2l)[tid];
    ((i32x4*)sW)[tid + 1024] = ((const i32x4*)Wt2l)[tid + 1024];
    ((i32x4*)sW)[tid + 2048] = ((const i32x4*)Wt2r)[tid];
    ((i32x4*)sW)[tid + 3072] = ((const i32x4*)Wt2r)[tid + 1024];
    __syncthreads();   // B1

    // phase A: sotu_h = relu(meanXrh@W2l + x_sotu@W2r + b2) -> tile
    {
        f32x4 acc[8];
#pragma unroll
        for (int cf = 0; cf < 8; ++cf) acc[cf] = ((const f32x4*)b2)[cf * 4 + g];
        const i32x4* a1r = (const i32x4*)(meanXrh + (size_t)rl * 64);
        const f32x4* xr = (const f32x4*)(xs + (size_t)rl * 128);
#pragma unroll
        for (int ks = 0; ks < 4; ++ks) {
            Frag mf; mf.i = a1r[ks * 4 + g];
            f32x4 fa = xr[ks * 8 + g * 2], fb = xr[ks * 8 + g * 2 + 1];
            Frag xf;
            i32x4 t = { (int)packbf(fa.x, fa.y), (int)packbf(fa.z, fa.w),
                        (int)packbf(fb.x, fb.y), (int)packbf(fb.z, fb.w) };
            xf.i = t;
#pragma unroll
            for (int cf = 0; cf < 8; ++cf) {
                int off = (((cf * 16 + ln) << 8) + (ks << 6) + (g << 4)) ^ swzW;
                Frag wa; wa.i = *(const i32x4*)(sW + off);
                Frag wb; wb.i = *(const i32x4*)(sW + 32768 + off);
                acc[cf] = __builtin_amdgcn_mfma_f32_16x16x32_bf16(wa.v, mf.v, acc[cf], 0, 0, 0);
                acc[cf] = __builtin_amdgcn_mfma_f32_16x16x32_bf16(wb.v, xf.v, acc[cf], 0, 0, 0);
            }
        }
#pragma unroll
        for (int cf = 0; cf < 8; ++cf) {
            u32x2 o;
            o.x = packbf(fmaxf(acc[cf][0], 0.f), fmaxf(acc[cf][1], 0.f));
            o.y = packbf(fmaxf(acc[cf][2], 0.f), fmaxf(acc[cf][3], 0.f));
            *(u32x2*)&tile[ln * 64 + ((cf * 8 + g * 2) ^ swz)] = o;
        }
    }

    i32x4 mh[4];
    {
        const i32x4* hr = (const i32x4*)(meanH + (size_t)rl * 64);
#pragma unroll
        for (int ks = 0; ks < 4; ++ks) mh[ks] = hr[ks * 4 + g];
    }
    __syncthreads();   // B2
    ((i32x4*)sW)[tid]        = w3pre[0];
    ((i32x4*)sW)[tid + 1024] = w3pre[1];
    ((i32x4*)sW)[tid + 2048] = w3pre[2];
    ((i32x4*)sW)[tid + 3072] = w3pre[3];
    __syncthreads();   // B3

    // phase B: h2 = relu(meanH@W3l + sotu_h@W3r + b3) -> tile (in place)
    {
        f32x4 acc2[8];
#pragma unroll
        for (int cf = 0; cf < 8; ++cf) acc2[cf] = ((const f32x4*)b3)[cf * 4 + g];
#pragma unroll
        for (int ks = 0; ks < 4; ++ks) {
            Frag mf; mf.i = mh[ks];
            Frag sf; sf.i = *(const i32x4*)&tile[ln * 64 + ((ks * 16 + g * 4) ^ swz)];
#pragma unroll
            for (int cf = 0; cf < 8; ++cf) {
                int off = (((cf * 16 + ln) << 8) + (ks << 6) + (g << 4)) ^ swzW;
                Frag wl; wl.i = *(const i32x4*)(sW + off);
                Frag wr; wr.i = *(const i32x4*)(sW + 32768 + off);
                acc2[cf] = __builtin_amdgcn_mfma_f32_16x16x32_bf16(wl.v, mf.v, acc2[cf], 0, 0, 0);
                acc2[cf] = __builtin_amdgcn_mfma_f32_16x16x32_bf16(wr.v, sf.v, acc2[cf], 0, 0, 0);
            }
        }
#pragma unroll
        for (int cf = 0; cf < 8; ++cf) {
            u32x2 o;
            o.x = packbf(fmaxf(acc2[cf][0], 0.f), fmaxf(acc2[cf][1], 0.f));
            o.y = packbf(fmaxf(acc2[cf][2], 0.f), fmaxf(acc2[cf][3], 0.f));
            *(u32x2*)&tile[ln * 64 + ((cf * 8 + g * 2) ^ swz)] = o;
        }
    }
    __syncthreads();   // B4
    ((i32x4*)sW)[tid] = wlpre;
    __syncthreads();   // B5

    // phase C: out = h2 @ Wlin + blin
    f32x4 aL[4];
#pragma unroll
    for (int cf = 0; cf < 4; ++cf) aL[cf] = ((const f32x4*)blin)[cf * 4 + g];
#pragma unroll
    for (int ks = 0; ks < 4; ++ks) {
        Frag hf; hf.i = *(const i32x4*)&tile[ln * 64 + ((ks * 16 + g * 4) ^ swz)];
#pragma unroll
        for (int cf = 0; cf < 4; ++cf) {
            int off = (((cf * 16 + ln) << 8) + (ks << 6) + (g << 4)) ^ swzW;
            Frag wf; wf.i = *(const i32x4*)(sW + off);
            aL[cf] = __builtin_amdgcn_mfma_f32_16x16x32_bf16(wf.v, hf.v, aL[cf], 0, 0, 0);
        }
    }
    if (row < M) {
        float* orow = out + (size_t)row * OUTC;
#pragma unroll
        for (int cf = 0; cf < 4; ++cf)
            *(f32x4*)(orow + cf * 16 + g * 4) = aL[cf];
    }
}

extern "C" void kernel_launch(void* const* d_in, const int* in_sizes, int n_in,
                              void* d_out, int out_size, void* d_ws, size_t ws_size,
                              hipStream_t stream)
{
    const float* x_taxon = (const float*)d_in[0];
    const float* x_sotu  = (const float*)d_in[1];
    const int* hp_src = (const int*)d_in[2];
    const int* hp_dst = (const int*)d_in[3];
    const int* rh_src = (const int*)d_in[4];
    const int* rh_dst = (const int*)d_in[5];
    const float* W1l = (const float*)d_in[6];
    const float* W1r = (const float*)d_in[7];
    const float* b1  = (const float*)d_in[8];
    const float* W2l = (const float*)d_in[9];
    const float* W2r = (const float*)d_in[10];
    const float* b2  = (const float*)d_in[11];
    const float* W3l = (const float*)d_in[12];
    const float* W3r = (const float*)d_in[13];
    const float* b3  = (const float*)d_in[14];
    const float* Wlin = (const float*)d_in[15];
    const float* blin = (const float*)d_in[16];
    float* out = (float*)d_out;

    // ---- workspace layout (bytes), peak ~189.5 MB ----
    char* ws = (char*)d_ws;
    unsigned* X2      = (unsigned*)(ws);                  // [100K][128] xt|taxon_h interleaved
    unsigned* meanXrh = (unsigned*)(ws + 51200000);       // [200K][64]; ebuf overlays (dead first)
    unsigned* meanH   = (unsigned*)(ws + 102400000);      // [200K][64]
    unsigned long long* ebuf = (unsigned long long*)(ws + 51200000);  // 17.6MB, dead before aggMean2
    int*      sorted_all = (int*)(ws + 179200000);        // [E_ALL] 8.8MB
    unsigned* row_ptr = (unsigned*)(ws + 188000000);      // [300001]
    unsigned* bcnt    = (unsigned*)(ws + 189200128);      // [160]
    unsigned* bcursor = (unsigned*)(ws + 189200768);      // [160]
    unsigned* bstart  = (unsigned*)(ws + 189201408);      // [160]
    unsigned short* wtbase = (unsigned short*)(ws + 189202048);
    unsigned short* Wt1l = wtbase;
    unsigned short* Wt1r = wtbase + 16384;
    unsigned short* Wt2l = wtbase + 32768;
    unsigned short* Wt2r = wtbase + 49152;
    unsigned short* Wt3l = wtbase + 65536;
    unsigned short* Wt3r = wtbase + 81920;
    unsigned short* Wtlin = wtbase + 98304;

    // zero bcnt only
    hipMemsetAsync(bcnt, 0, 640, stream);

    // ---- unified CSR build (300K rows, 2.2M edges, 147 buckets) ----
    countAll_kernel<<<512, 256, 0, stream>>>(hp_dst, rh_dst, bcnt);
    scanB147_kernel<<<1, 256, 0, stream>>>(bcnt, bcursor, bstart, row_ptr);
    partition_kernel<<<(E_ALL + 4095) / 4096, 256, 0, stream>>>(
        hp_src, hp_dst, rh_src, rh_dst, bcursor, ebuf);
    fillB_kernel<<<NBUCK, 256, 0, stream>>>(ebuf, bstart, row_ptr, sorted_all);

    // ---- weight prep ----
    wprep_all_kernel<<<(6 * 16384 + 8192 + 255) / 256, 256, 0, stream>>>(
        W1l, W1r, W2l, W2r, W3l, W3r, Wlin, wtbase);

    // ---- fused hp-mean + taxon_h GEMM -> full X2 rows ----
    gemmTh2_kernel<<<(N_TAXON + 255) / 256, 1024, 0, stream>>>(
        x_taxon, row_ptr, sorted_all, Wt1l, Wt1r, b1, X2, N_TAXON);

    // ---- merged rh gather: meanXrh + meanH in one walk ----
    aggMean2_kernel<<<N_SOTU / 4, 256, 0, stream>>>(
        X2, row_ptr + N_TAXON, sorted_all, meanXrh, meanH);

    // ---- megaTail: sotu_h -> h2 (LDS) -> out ----
    megaTail_kernel<<<(N_SOTU + 255) / 256, 1024, 0, stream>>>(
        meanXrh, x_sotu, meanH, Wt2l, Wt2r, Wt3l, Wt3r, Wtlin, b2, b3, blin, out, N_SOTU);
}

// Round 17
// 444.377 us; speedup vs baseline: 1.1965x; 1.0014x over previous
//
#include <hip/hip_runtime.h>
#include <hip/hip_bf16.h>

#define D 128
#define N_TAXON 100000
#define N_SOTU 200000
#define N_ALL 300000
#define E_HP 200000
#define E_RH 2000000
#define E_ALL 2200000
#define OUTC 64
#define NBUCK 147     // ceil(300000 / 2048)
#define BSHIFT 11

typedef __hip_bfloat16 bf16;
typedef __bf16 bf16v8 __attribute__((ext_vector_type(8)));
typedef float f32x4 __attribute__((ext_vector_type(4)));
typedef int i32x4 __attribute__((ext_vector_type(4)));
typedef unsigned u32x2 __attribute__((ext_vector_type(2)));

union Frag { i32x4 i; bf16v8 v; };

__device__ __forceinline__ float bflo(unsigned u) { return __uint_as_float(u << 16); }
__device__ __forceinline__ float bfhi(unsigned u) { return __uint_as_float(u & 0xffff0000u); }

__device__ __forceinline__ unsigned short f2bf(float x) {
    unsigned u = __float_as_uint(x);
    unsigned r = (u + 0x7fffu + ((u >> 16) & 1u)) >> 16;   // round-to-nearest-even
    return (unsigned short)r;
}
__device__ __forceinline__ unsigned packbf(float a, float b) {
    return (unsigned)f2bf(a) | ((unsigned)f2bf(b) << 16);
}

// ---------------- unified bucket histogram over hp + rh ----------------
__global__ __launch_bounds__(256) void countAll_kernel(const int* __restrict__ hp_dst,
                                                       const int* __restrict__ rh_dst,
                                                       unsigned* __restrict__ bcnt)
{
    __shared__ unsigned hist[NBUCK];
    for (int i = threadIdx.x; i < NBUCK; i += 256) hist[i] = 0;
    __syncthreads();
    int stride = gridDim.x * 256;
    for (int e = blockIdx.x * 256 + threadIdx.x; e < E_HP; e += stride)
        atomicAdd(&hist[hp_dst[e] >> BSHIFT], 1u);
    for (int e = blockIdx.x * 256 + threadIdx.x; e < E_RH; e += stride)
        atomicAdd(&hist[(N_TAXON + rh_dst[e]) >> BSHIFT], 1u);
    __syncthreads();
    for (int i = threadIdx.x; i < NBUCK; i += 256) atomicAdd(&bcnt[i], hist[i]);
}

// ---------------- bucket prefix (+ final row_ptr sentinel) ----------------
__global__ __launch_bounds__(256) void scanB147_kernel(const unsigned* __restrict__ bcnt,
                                                       unsigned* __restrict__ bcursor,
                                                       unsigned* __restrict__ bstart,
                                                       unsigned* __restrict__ row_ptr)
{
    if (threadIdx.x == 0) {
        unsigned acc = 0;
        for (int b = 0; b < NBUCK; ++b) {
            unsigned t = bcnt[b];
            bcursor[b] = acc; bstart[b] = acc; acc += t;
        }
        bstart[NBUCK] = acc;
        row_ptr[N_ALL] = E_ALL;   // sentinel
    }
}

// ---------------- partition all edges into global-dst buckets ----------------
__global__ __launch_bounds__(256) void partition_kernel(
    const int* __restrict__ hp_src, const int* __restrict__ hp_dst,
    const int* __restrict__ rh_src, const int* __restrict__ rh_dst,
    unsigned* __restrict__ bcursor, unsigned long long* __restrict__ ebuf)
{
    __shared__ unsigned hist[NBUCK];
    __shared__ unsigned lcur[NBUCK];
    int base = blockIdx.x * 4096;
    for (int i = threadIdx.x; i < NBUCK; i += 256) hist[i] = 0;
    __syncthreads();
    int s[16], d[16];
#pragma unroll
    for (int k = 0; k < 16; ++k) {
        int e = base + k * 256 + threadIdx.x;
        if (e < E_HP) {
            s[k] = hp_src[e]; d[k] = hp_dst[e];
            atomicAdd(&hist[d[k] >> BSHIFT], 1u);
        } else if (e < E_ALL) {
            s[k] = rh_src[e - E_HP]; d[k] = N_TAXON + rh_dst[e - E_HP];
            atomicAdd(&hist[d[k] >> BSHIFT], 1u);
        } else d[k] = -1;
    }
    __syncthreads();
    for (int i = threadIdx.x; i < NBUCK; i += 256)
        lcur[i] = atomicAdd(&bcursor[i], hist[i]);
    __syncthreads();
#pragma unroll
    for (int k = 0; k < 16; ++k) {
        if (d[k] >= 0) {
            unsigned slot = atomicAdd(&lcur[d[k] >> BSHIFT], 1u);
            ebuf[slot] = ((unsigned long long)(unsigned)d[k] << 32) | (unsigned)s[k];
        }
    }
}

// ---------------- per-bucket: LDS count + scan -> row_ptr + dense fill ----------------
__global__ __launch_bounds__(256) void fillB_kernel(const unsigned long long* __restrict__ ebuf,
                                                    const unsigned* __restrict__ bstart,
                                                    unsigned* __restrict__ row_ptr,
                                                    int* __restrict__ sorted_all)
{
    __shared__ unsigned hist[1 << BSHIFT];   // 8KB: counts -> absolute cursors
    __shared__ unsigned wsum[4];
    int c = blockIdx.x;
    int dbase = c << BSHIFT;
    for (int i = threadIdx.x; i < (1 << BSHIFT); i += 256) hist[i] = 0;
    __syncthreads();
    unsigned e0 = bstart[c], e1 = bstart[c + 1];
    for (unsigned e = e0 + threadIdx.x; e < e1; e += 256)
        atomicAdd(&hist[(unsigned)(ebuf[e] >> 32) - dbase], 1u);
    __syncthreads();
    int base8 = threadIdx.x * 8;
    unsigned loc[8], s = 0;
#pragma unroll
    for (int i = 0; i < 8; ++i) { loc[i] = s; s += hist[base8 + i]; }
    int lane = threadIdx.x & 63, wv = threadIdx.x >> 6;
    unsigned sc = s;
    for (int off = 1; off < 64; off <<= 1) {
        unsigned t = __shfl_up(sc, off, 64);
        if (lane >= off) sc += t;
    }
    if (lane == 63) wsum[wv] = sc;
    __syncthreads();
    unsigned woff = 0;
    for (int w = 0; w < wv; ++w) woff += wsum[w];
    unsigned tbase = e0 + woff + sc - s;   // absolute exclusive prefix in sorted_all
#pragma unroll
    for (int i = 0; i < 8; ++i) {
        int dd = dbase + base8 + i;
        unsigned p = tbase + loc[i];
        if (dd < N_ALL) row_ptr[dd] = p;
        hist[base8 + i] = p;               // becomes the fill cursor
    }
    __syncthreads();
    for (unsigned e = e0 + threadIdx.x; e < e1; e += 256) {
        unsigned long long v = ebuf[e];
        unsigned pos = atomicAdd(&hist[(unsigned)(v >> 32) - dbase], 1u);
        sorted_all[pos] = (int)(unsigned)v;
    }
}

// ---------------- all weights: transpose + bf16 + XOR-swizzle ----------------
__global__ __launch_bounds__(256) void wprep_all_kernel(
    const float* __restrict__ W1l, const float* __restrict__ W1r,
    const float* __restrict__ W2l, const float* __restrict__ W2r,
    const float* __restrict__ W3l, const float* __restrict__ W3r,
    const float* __restrict__ Wlin, unsigned short* __restrict__ wtbase)
{
    int e = blockIdx.x * 256 + threadIdx.x;
    if (e >= 6 * 16384 + 8192) return;
    const float* srcs[7] = { W1l, W1r, W2l, W2r, W3l, W3r, Wlin };
    int m = e >> 14;
    int local = (m < 6) ? (e & 16383) : (e - 98304);
    int N = (m < 6) ? 128 : 64;
    int k = local / N, col = local - k * N;
    unsigned short* dst = wtbase + ((m < 6) ? m * 16384 : 98304);
    dst[(col * 128 + k) ^ ((col & 7) << 3)] = f2bf(srcs[m][local]);
}

// ---------------- gemmTh2: fused hp-mean gather + dual GEMM -> full X2 rows ----------------
// 1024 threads, 16 waves, 256 rows/block; gather deg~2 per row (cheap, wave-local)
__global__ __launch_bounds__(1024) void gemmTh2_kernel(
    const float* __restrict__ X /*x_taxon f32*/,
    const unsigned* __restrict__ rp, const int* __restrict__ nbr,
    const unsigned short* __restrict__ WtA, const unsigned short* __restrict__ WtB,
    const float* __restrict__ bias, unsigned* __restrict__ X2, int M)
{
    __shared__ char sW[65536];
    __shared__ unsigned tiles[16 * 1024];
    int tid = threadIdx.x;
    ((i32x4*)sW)[tid]        = ((const i32x4*)WtA)[tid];
    ((i32x4*)sW)[tid + 1024] = ((const i32x4*)WtA)[tid + 1024];
    ((i32x4*)sW)[tid + 2048] = ((const i32x4*)WtB)[tid];
    ((i32x4*)sW)[tid + 3072] = ((const i32x4*)WtB)[tid + 1024];

    int wave = tid >> 6, lane = tid & 63;
    int ln = lane & 15, g = lane >> 4;
    int rbase = blockIdx.x * 256 + wave * 16;
    unsigned* tile = tiles + wave * 1024;

    // ---- gather phase: mean of hp neighbors for the wave's 16 rows ----
    for (int i = 0; i < 16; ++i) {
        int r = rbase + i;
        float a0 = 0.f, a1 = 0.f;
        if (r < M) {
            unsigned beg = rp[r], end = rp[r + 1];
            unsigned u = beg;
            for (; u + 2 <= end; u += 2) {
                float2 A = ((const float2*)X)[(size_t)nbr[u] * 64 + lane];
                float2 B = ((const float2*)X)[(size_t)nbr[u + 1] * 64 + lane];
                a0 += A.x + B.x; a1 += A.y + B.y;
            }
            if (u < end) {
                float2 A = ((const float2*)X)[(size_t)nbr[u] * 64 + lane];
                a0 += A.x; a1 += A.y;
            }
            unsigned cdeg = end - beg;
            float inv = 1.f / (float)(cdeg ? cdeg : 1u);
            a0 *= inv; a1 *= inv;
        }
        tile[i * 64 + (lane ^ ((i & 7) << 2))] = packbf(a0, a1);
    }
    __syncthreads();

    // ---- GEMM phase ----
    int row = rbase + ln;
    int rl = row < M ? row : M - 1;
    int swzW = (ln & 7) << 4;
    int swz = (ln & 7) << 2;

    f32x4 acc[8];
#pragma unroll
    for (int cf = 0; cf < 8; ++cf) acc[cf] = ((const f32x4*)bias)[cf * 4 + g];

    const f32x4* xr = (const f32x4*)(X + (size_t)rl * 128);
    unsigned* orow = X2 + (size_t)row * 128;
    i32x4 xpk[4];
#pragma unroll
    for (int ks = 0; ks < 4; ++ks) {
        Frag mf; mf.i = *(const i32x4*)&tile[ln * 64 + ((ks * 16 + g * 4) ^ swz)];
        f32x4 fa = xr[ks * 8 + g * 2], fb = xr[ks * 8 + g * 2 + 1];
        Frag xf;
        i32x4 t = { (int)packbf(fa.x, fa.y), (int)packbf(fa.z, fa.w),
                    (int)packbf(fb.x, fb.y), (int)packbf(fb.z, fb.w) };
        xf.i = t; xpk[ks] = t;
#pragma unroll
        for (int cf = 0; cf < 8; ++cf) {
            int off = (((cf * 16 + ln) << 8) + (ks << 6) + (g << 4)) ^ swzW;
            Frag wa; wa.i = *(const i32x4*)(sW + off);
            Frag wb; wb.i = *(const i32x4*)(sW + 32768 + off);
            acc[cf] = __builtin_amdgcn_mfma_f32_16x16x32_bf16(wa.v, mf.v, acc[cf], 0, 0, 0);
            acc[cf] = __builtin_amdgcn_mfma_f32_16x16x32_bf16(wb.v, xf.v, acc[cf], 0, 0, 0);
        }
    }

    if (row < M) {
#pragma unroll
        for (int ks = 0; ks < 4; ++ks) {
            int p0 = 16 * ks + 4 * g;
            orow[(p0 + 0) * 2] = (unsigned)xpk[ks][0];
            orow[(p0 + 1) * 2] = (unsigned)xpk[ks][1];
            orow[(p0 + 2) * 2] = (unsigned)xpk[ks][2];
            orow[(p0 + 3) * 2] = (unsigned)xpk[ks][3];
        }
#pragma unroll
        for (int cf = 0; cf < 8; ++cf) {
            int p = cf * 8 + g * 2;
            orow[p * 2 + 1]       = packbf(fmaxf(acc[cf][0], 0.f), fmaxf(acc[cf][1], 0.f));
            orow[(p + 1) * 2 + 1] = packbf(fmaxf(acc[cf][2], 0.f), fmaxf(acc[cf][3], 0.f));
        }
    }
}

// ---------------- merged rh gather: meanXrh + meanH in ONE walk (XCD-swizzled) ----------------
__global__ __launch_bounds__(256) void aggMean2_kernel(
    const unsigned* __restrict__ X2, const unsigned* __restrict__ rp,
    const int* __restrict__ nbr,
    unsigned* __restrict__ meanXrh, unsigned* __restrict__ meanH)
{
    int wave = threadIdx.x >> 6, lane = threadIdx.x & 63;
    int bid = (blockIdx.x & 7) * 6250 + (blockIdx.x >> 3);   // grid = 50000
    int r = bid * 4 + wave;
    unsigned beg = rp[r], end = rp[r + 1];
    float a0 = 0.f, a1 = 0.f, a2 = 0.f, a3 = 0.f;
    unsigned u = beg;
    for (; u + 2 <= end; u += 2) {
        int j0 = nbr[u], j1 = nbr[u + 1];
        u32x2 A = *(const u32x2*)(X2 + (size_t)j0 * 128 + lane * 2);
        u32x2 B = *(const u32x2*)(X2 + (size_t)j1 * 128 + lane * 2);
        a0 += bflo(A.x) + bflo(B.x); a1 += bfhi(A.x) + bfhi(B.x);
        a2 += bflo(A.y) + bflo(B.y); a3 += bfhi(A.y) + bfhi(B.y);
    }
    if (u < end) {
        u32x2 A = *(const u32x2*)(X2 + (size_t)nbr[u] * 128 + lane * 2);
        a0 += bflo(A.x); a1 += bfhi(A.x); a2 += bflo(A.y); a3 += bfhi(A.y);
    }
    unsigned c = end - beg;
    float inv = 1.f / (float)(c ? c : 1u);
    meanXrh[(size_t)r * 64 + lane] = packbf(a0 * inv, a1 * inv);
    meanH[(size_t)r * 64 + lane]   = packbf(a2 * inv, a3 * inv);
}

// ---------------- megaTail: sotu_h (LDS tiles) -> h2 (in-place) -> out ----------------
__global__ __launch_bounds__(1024) void megaTail_kernel(
    const unsigned* __restrict__ meanXrh, const float* __restrict__ xs,
    const unsigned* __restrict__ meanH,
    const unsigned short* __restrict__ Wt2l, const unsigned short* __restrict__ Wt2r,
    const unsigned short* __restrict__ Wt3l, const unsigned short* __restrict__ Wt3r,
    const unsigned short* __restrict__ Wtlin,
    const float* __restrict__ b2, const float* __restrict__ b3,
    const float* __restrict__ blin, float* __restrict__ out, int M)
{
    __shared__ char sW[65536];
    __shared__ unsigned tiles[16 * 1024];
    int tid = threadIdx.x;
    int wave = tid >> 6, lane = tid & 63;
    int ln = lane & 15, g = lane >> 4;
    int row = blockIdx.x * 256 + wave * 16 + ln;
    int rl = row < M ? row : M - 1;
    int swzW = (ln & 7) << 4;
    int swz = (ln & 7) << 2;
    unsigned* tile = tiles + wave * 1024;

    i32x4 w3pre[4], wlpre;
    w3pre[0] = ((const i32x4*)Wt3l)[tid];
    w3pre[1] = ((const i32x4*)Wt3l)[tid + 1024];
    w3pre[2] = ((const i32x4*)Wt3r)[tid];
    w3pre[3] = ((const i32x4*)Wt3r)[tid + 1024];
    wlpre    = ((const i32x4*)Wtlin)[tid];

    ((i32x4*)sW)[tid]        = ((const i32x4*)Wt2l)[tid];
    ((i32x4*)sW)[tid + 1024] = ((const i32x4*)Wt2l)[tid + 1024];
    ((i32x4*)sW)[tid + 2048] = ((const i32x4*)Wt2r)[tid];
    ((i32x4*)sW)[tid + 3072] = ((const i32x4*)Wt2r)[tid + 1024];
    __syncthreads();   // B1

    // phase A: sotu_h = relu(meanXrh@W2l + x_sotu@W2r + b2) -> tile
    {
        f32x4 acc[8];
#pragma unroll
        for (int cf = 0; cf < 8; ++cf) acc[cf] = ((const f32x4*)b2)[cf * 4 + g];
        const i32x4* a1r = (const i32x4*)(meanXrh + (size_t)rl * 64);
        const f32x4* xr = (const f32x4*)(xs + (size_t)rl * 128);
#pragma unroll
        for (int ks = 0; ks < 4; ++ks) {
            Frag mf; mf.i = a1r[ks * 4 + g];
            f32x4 fa = xr[ks * 8 + g * 2], fb = xr[ks * 8 + g * 2 + 1];
            Frag xf;
            i32x4 t = { (int)packbf(fa.x, fa.y), (int)packbf(fa.z, fa.w),
                        (int)packbf(fb.x, fb.y), (int)packbf(fb.z, fb.w) };
            xf.i = t;
#pragma unroll
            for (int cf = 0; cf < 8; ++cf) {
                int off = (((cf * 16 + ln) << 8) + (ks << 6) + (g << 4)) ^ swzW;
                Frag wa; wa.i = *(const i32x4*)(sW + off);
                Frag wb; wb.i = *(const i32x4*)(sW + 32768 + off);
                acc[cf] = __builtin_amdgcn_mfma_f32_16x16x32_bf16(wa.v, mf.v, acc[cf], 0, 0, 0);
                acc[cf] = __builtin_amdgcn_mfma_f32_16x16x32_bf16(wb.v, xf.v, acc[cf], 0, 0, 0);
            }
        }
#pragma unroll
        for (int cf = 0; cf < 8; ++cf) {
            u32x2 o;
            o.x = packbf(fmaxf(acc[cf][0], 0.f), fmaxf(acc[cf][1], 0.f));
            o.y = packbf(fmaxf(acc[cf][2], 0.f), fmaxf(acc[cf][3], 0.f));
            *(u32x2*)&tile[ln * 64 + ((cf * 8 + g * 2) ^ swz)] = o;
        }
    }

    i32x4 mh[4];
    {
        const i32x4* hr = (const i32x4*)(meanH + (size_t)rl * 64);
#pragma unroll
        for (int ks = 0; ks < 4; ++ks) mh[ks] = hr[ks * 4 + g];
    }
    __syncthreads();   // B2
    ((i32x4*)sW)[tid]        = w3pre[0];
    ((i32x4*)sW)[tid + 1024] = w3pre[1];
    ((i32x4*)sW)[tid + 2048] = w3pre[2];
    ((i32x4*)sW)[tid + 3072] = w3pre[3];
    __syncthreads();   // B3

    // phase B: h2 = relu(meanH@W3l + sotu_h@W3r + b3) -> tile (in place)
    {
        f32x4 acc2[8];
#pragma unroll
        for (int cf = 0; cf < 8; ++cf) acc2[cf] = ((const f32x4*)b3)[cf * 4 + g];
#pragma unroll
        for (int ks = 0; ks < 4; ++ks) {
            Frag mf; mf.i = mh[ks];
            Frag sf; sf.i = *(const i32x4*)&tile[ln * 64 + ((ks * 16 + g * 4) ^ swz)];
#pragma unroll
            for (int cf = 0; cf < 8; ++cf) {
                int off = (((cf * 16 + ln) << 8) + (ks << 6) + (g << 4)) ^ swzW;
                Frag wl; wl.i = *(const i32x4*)(sW + off);
                Frag wr; wr.i = *(const i32x4*)(sW + 32768 + off);
                acc2[cf] = __builtin_amdgcn_mfma_f32_16x16x32_bf16(wl.v, mf.v, acc2[cf], 0, 0, 0);
                acc2[cf] = __builtin_amdgcn_mfma_f32_16x16x32_bf16(wr.v, sf.v, acc2[cf], 0, 0, 0);
            }
        }
#pragma unroll
        for (int cf = 0; cf < 8; ++cf) {
            u32x2 o;
            o.x = packbf(fmaxf(acc2[cf][0], 0.f), fmaxf(acc2[cf][1], 0.f));
            o.y = packbf(fmaxf(acc2[cf][2], 0.f), fmaxf(acc2[cf][3], 0.f));
            *(u32x2*)&tile[ln * 64 + ((cf * 8 + g * 2) ^ swz)] = o;
        }
    }
    __syncthreads();   // B4
    ((i32x4*)sW)[tid] = wlpre;
    __syncthreads();   // B5

    // phase C: out = h2 @ Wlin + blin
    f32x4 aL[4];
#pragma unroll
    for (int cf = 0; cf < 4; ++cf) aL[cf] = ((const f32x4*)blin)[cf * 4 + g];
#pragma unroll
    for (int ks = 0; ks < 4; ++ks) {
        Frag hf; hf.i = *(const i32x4*)&tile[ln * 64 + ((ks * 16 + g * 4) ^ swz)];
#pragma unroll
        for (int cf = 0; cf < 4; ++cf) {
            int off = (((cf * 16 + ln) << 8) + (ks << 6) + (g << 4)) ^ swzW;
            Frag wf; wf.i = *(const i32x4*)(sW + off);
            aL[cf] = __builtin_amdgcn_mfma_f32_16x16x32_bf16(wf.v, hf.v, aL[cf], 0, 0, 0);
        }
    }
    if (row < M) {
        float* orow = out + (size_t)row * OUTC;
#pragma unroll
        for (int cf = 0; cf < 4; ++cf)
            *(f32x4*)(orow + cf * 16 + g * 4) = aL[cf];
    }
}

extern "C" void kernel_launch(void* const* d_in, const int* in_sizes, int n_in,
                              void* d_out, int out_size, void* d_ws, size_t ws_size,
                              hipStream_t stream)
{
    const float* x_taxon = (const float*)d_in[0];
    const float* x_sotu  = (const float*)d_in[1];
    const int* hp_src = (const int*)d_in[2];
    const int* hp_dst = (const int*)d_in[3];
    const int* rh_src = (const int*)d_in[4];
    const int* rh_dst = (const int*)d_in[5];
    const float* W1l = (const float*)d_in[6];
    const float* W1r = (const float*)d_in[7];
    const float* b1  = (const float*)d_in[8];
    const float* W2l = (const float*)d_in[9];
    const float* W2r = (const float*)d_in[10];
    const float* b2  = (const float*)d_in[11];
    const float* W3l = (const float*)d_in[12];
    const float* W3r = (const float*)d_in[13];
    const float* b3  = (const float*)d_in[14];
    const float* Wlin = (const float*)d_in[15];
    const float* blin = (const float*)d_in[16];
    float* out = (float*)d_out;

    // ---- workspace layout (bytes), peak ~189.5 MB ----
    char* ws = (char*)d_ws;
    unsigned* X2      = (unsigned*)(ws);                  // [100K][128] xt|taxon_h interleaved
    unsigned* meanXrh = (unsigned*)(ws + 51200000);       // [200K][64]; ebuf overlays (dead first)
    unsigned* meanH   = (unsigned*)(ws + 102400000);      // [200K][64]
    unsigned long long* ebuf = (unsigned long long*)(ws + 51200000);  // 17.6MB, dead before aggMean2
    int*      sorted_all = (int*)(ws + 179200000);        // [E_ALL] 8.8MB
    unsigned* row_ptr = (unsigned*)(ws + 188000000);      // [300001]
    unsigned* bcnt    = (unsigned*)(ws + 189200128);      // [160]
    unsigned* bcursor = (unsigned*)(ws + 189200768);      // [160]
    unsigned* bstart  = (unsigned*)(ws + 189201408);      // [160]
    unsigned short* wtbase = (unsigned short*)(ws + 189202048);
    unsigned short* Wt1l = wtbase;
    unsigned short* Wt1r = wtbase + 16384;
    unsigned short* Wt2l = wtbase + 32768;
    unsigned short* Wt2r = wtbase + 49152;
    unsigned short* Wt3l = wtbase + 65536;
    unsigned short* Wt3r = wtbase + 81920;
    unsigned short* Wtlin = wtbase + 98304;

    // zero bcnt only
    hipMemsetAsync(bcnt, 0, 640, stream);

    // ---- unified CSR build (300K rows, 2.2M edges, 147 buckets) ----
    countAll_kernel<<<512, 256, 0, stream>>>(hp_dst, rh_dst, bcnt);
    scanB147_kernel<<<1, 256, 0, stream>>>(bcnt, bcursor, bstart, row_ptr);
    partition_kernel<<<(E_ALL + 4095) / 4096, 256, 0, stream>>>(
        hp_src, hp_dst, rh_src, rh_dst, bcursor, ebuf);
    fillB_kernel<<<NBUCK, 256, 0, stream>>>(ebuf, bstart, row_ptr, sorted_all);

    // ---- weight prep ----
    wprep_all_kernel<<<(6 * 16384 + 8192 + 255) / 256, 256, 0, stream>>>(
        W1l, W1r, W2l, W2r, W3l, W3r, Wlin, wtbase);

    // ---- fused hp-mean + taxon_h GEMM -> full X2 rows ----
    gemmTh2_kernel<<<(N_TAXON + 255) / 256, 1024, 0, stream>>>(
        x_taxon, row_ptr, sorted_all, Wt1l, Wt1r, b1, X2, N_TAXON);

    // ---- merged rh gather: meanXrh + meanH in one walk ----
    aggMean2_kernel<<<N_SOTU / 4, 256, 0, stream>>>(
        X2, row_ptr + N_TAXON, sorted_all, meanXrh, meanH);

    // ---- megaTail: sotu_h -> h2 (LDS) -> out ----
    megaTail_kernel<<<(N_SOTU + 255) / 256, 1024, 0, stream>>>(
        meanXrh, x_sotu, meanH, Wt2l, Wt2r, Wt3l, Wt3r, Wtlin, b2, b3, blin, out, N_SOTU);
}

// Round 18
// 414.045 us; speedup vs baseline: 1.2842x; 1.0733x over previous
//
#include <hip/hip_runtime.h>
#include <hip/hip_bf16.h>

#define D 128
#define N_TAXON 100000
#define N_SOTU 200000
#define N_ALL 300000
#define E_HP 200000
#define E_RH 2000000
#define E_ALL 2200000
#define OUTC 64
#define NBUCK 147     // ceil(300000 / 2048)
#define BSHIFT 11
#define BCAP 24576    // fixed bucket capacity (rh mean 20480, +28 sigma)

typedef __hip_bfloat16 bf16;
typedef __bf16 bf16v8 __attribute__((ext_vector_type(8)));
typedef float f32x4 __attribute__((ext_vector_type(4)));
typedef int i32x4 __attribute__((ext_vector_type(4)));
typedef unsigned u32x2 __attribute__((ext_vector_type(2)));

union Frag { i32x4 i; bf16v8 v; };

__device__ __forceinline__ float bflo(unsigned u) { return __uint_as_float(u << 16); }
__device__ __forceinline__ float bfhi(unsigned u) { return __uint_as_float(u & 0xffff0000u); }

__device__ __forceinline__ unsigned short f2bf(float x) {
    unsigned u = __float_as_uint(x);
    unsigned r = (u + 0x7fffu + ((u >> 16) & 1u)) >> 16;   // round-to-nearest-even
    return (unsigned short)r;
}
__device__ __forceinline__ unsigned packbf(float a, float b) {
    return (unsigned)f2bf(a) | ((unsigned)f2bf(b) << 16);
}

// ---------------- partition all edges into fixed-capacity global-dst buckets ----------------
// ebuf entry: (dloc << 17) | src   (dloc < 2048, src < 131072)
__global__ __launch_bounds__(256) void partition_kernel(
    const int* __restrict__ hp_src, const int* __restrict__ hp_dst,
    const int* __restrict__ rh_src, const int* __restrict__ rh_dst,
    unsigned* __restrict__ bcnt, unsigned* __restrict__ ebuf)
{
    __shared__ unsigned hist[NBUCK];
    __shared__ unsigned lcur[NBUCK];
    int base = blockIdx.x * 4096;
    for (int i = threadIdx.x; i < NBUCK; i += 256) hist[i] = 0;
    __syncthreads();
    int s[16], d[16];
#pragma unroll
    for (int k = 0; k < 16; ++k) {
        int e = base + k * 256 + threadIdx.x;
        if (e < E_HP) {
            s[k] = hp_src[e]; d[k] = hp_dst[e];
            atomicAdd(&hist[d[k] >> BSHIFT], 1u);
        } else if (e < E_ALL) {
            s[k] = rh_src[e - E_HP]; d[k] = N_TAXON + rh_dst[e - E_HP];
            atomicAdd(&hist[d[k] >> BSHIFT], 1u);
        } else d[k] = -1;
    }
    __syncthreads();
    for (int i = threadIdx.x; i < NBUCK; i += 256)
        lcur[i] = atomicAdd(&bcnt[i], hist[i]);
    __syncthreads();
#pragma unroll
    for (int k = 0; k < 16; ++k) {
        if (d[k] >= 0) {
            int c = d[k] >> BSHIFT;
            unsigned slot = atomicAdd(&lcur[c], 1u);
            ebuf[(unsigned)c * BCAP + slot] =
                ((unsigned)(d[k] & ((1 << BSHIFT) - 1)) << 17) | (unsigned)s[k];
        }
    }
}

// ---------------- bucket prefix from actual counts (+ row_ptr sentinel) ----------------
__global__ __launch_bounds__(256) void scan147_kernel(const unsigned* __restrict__ bcnt,
                                                      unsigned* __restrict__ bstart,
                                                      unsigned* __restrict__ row_ptr)
{
    if (threadIdx.x == 0) {
        unsigned acc = 0;
        for (int b = 0; b < NBUCK; ++b) { bstart[b] = acc; acc += bcnt[b]; }
        bstart[NBUCK] = acc;
        row_ptr[N_ALL] = E_ALL;   // sentinel
    }
}

// ---------------- per-bucket: LDS count + scan -> row_ptr + dense fill ----------------
__global__ __launch_bounds__(256) void fillB_kernel(const unsigned* __restrict__ ebuf,
                                                    const unsigned* __restrict__ bcnt,
                                                    const unsigned* __restrict__ bstart,
                                                    unsigned* __restrict__ row_ptr,
                                                    int* __restrict__ sorted_all)
{
    __shared__ unsigned hist[1 << BSHIFT];   // 8KB: counts -> absolute cursors
    __shared__ unsigned wsum[4];
    int c = blockIdx.x;
    int dbase = c << BSHIFT;
    for (int i = threadIdx.x; i < (1 << BSHIFT); i += 256) hist[i] = 0;
    __syncthreads();
    const unsigned* eb = ebuf + (unsigned)c * BCAP;
    unsigned n = bcnt[c];
    for (unsigned e = threadIdx.x; e < n; e += 256)
        atomicAdd(&hist[eb[e] >> 17], 1u);
    __syncthreads();
    int base8 = threadIdx.x * 8;
    unsigned loc[8], s = 0;
#pragma unroll
    for (int i = 0; i < 8; ++i) { loc[i] = s; s += hist[base8 + i]; }
    int lane = threadIdx.x & 63, wv = threadIdx.x >> 6;
    unsigned sc = s;
    for (int off = 1; off < 64; off <<= 1) {
        unsigned t = __shfl_up(sc, off, 64);
        if (lane >= off) sc += t;
    }
    if (lane == 63) wsum[wv] = sc;
    __syncthreads();
    unsigned woff = 0;
    for (int w = 0; w < wv; ++w) woff += wsum[w];
    unsigned tbase = bstart[c] + woff + sc - s;   // absolute exclusive prefix
#pragma unroll
    for (int i = 0; i < 8; ++i) {
        int dd = dbase + base8 + i;
        unsigned p = tbase + loc[i];
        if (dd < N_ALL) row_ptr[dd] = p;
        hist[base8 + i] = p;                      // becomes the fill cursor
    }
    __syncthreads();
    for (unsigned e = threadIdx.x; e < n; e += 256) {
        unsigned v = eb[e];
        unsigned pos = atomicAdd(&hist[v >> 17], 1u);
        sorted_all[pos] = (int)(v & 0x1FFFFu);
    }
}

// ---------------- all weights: transpose + bf16 + XOR-swizzle ----------------
__global__ __launch_bounds__(256) void wprep_all_kernel(
    const float* __restrict__ W1l, const float* __restrict__ W1r,
    const float* __restrict__ W2l, const float* __restrict__ W2r,
    const float* __restrict__ W3l, const float* __restrict__ W3r,
    const float* __restrict__ Wlin, unsigned short* __restrict__ wtbase)
{
    int e = blockIdx.x * 256 + threadIdx.x;
    if (e >= 6 * 16384 + 8192) return;
    const float* srcs[7] = { W1l, W1r, W2l, W2r, W3l, W3r, Wlin };
    int m = e >> 14;
    int local = (m < 6) ? (e & 16383) : (e - 98304);
    int N = (m < 6) ? 128 : 64;
    int k = local / N, col = local - k * N;
    unsigned short* dst = wtbase + ((m < 6) ? m * 16384 : 98304);
    dst[(col * 128 + k) ^ ((col & 7) << 3)] = f2bf(srcs[m][local]);
}

// ---------------- gemmTh2: fused hp-mean gather + dual GEMM -> full X2 rows ----------------
__global__ __launch_bounds__(1024) void gemmTh2_kernel(
    const float* __restrict__ X /*x_taxon f32*/,
    const unsigned* __restrict__ rp, const int* __restrict__ nbr,
    const unsigned short* __restrict__ WtA, const unsigned short* __restrict__ WtB,
    const float* __restrict__ bias, unsigned* __restrict__ X2, int M)
{
    __shared__ char sW[65536];
    __shared__ unsigned tiles[16 * 1024];
    int tid = threadIdx.x;
    ((i32x4*)sW)[tid]        = ((const i32x4*)WtA)[tid];
    ((i32x4*)sW)[tid + 1024] = ((const i32x4*)WtA)[tid + 1024];
    ((i32x4*)sW)[tid + 2048] = ((const i32x4*)WtB)[tid];
    ((i32x4*)sW)[tid + 3072] = ((const i32x4*)WtB)[tid + 1024];

    int wave = tid >> 6, lane = tid & 63;
    int ln = lane & 15, g = lane >> 4;
    int rbase = blockIdx.x * 256 + wave * 16;
    unsigned* tile = tiles + wave * 1024;

    // gather phase: mean of hp neighbors for the wave's 16 rows (deg~2)
    for (int i = 0; i < 16; ++i) {
        int r = rbase + i;
        float a0 = 0.f, a1 = 0.f;
        if (r < M) {
            unsigned beg = rp[r], end = rp[r + 1];
            unsigned u = beg;
            for (; u + 2 <= end; u += 2) {
                float2 A = ((const float2*)X)[(size_t)nbr[u] * 64 + lane];
                float2 B = ((const float2*)X)[(size_t)nbr[u + 1] * 64 + lane];
                a0 += A.x + B.x; a1 += A.y + B.y;
            }
            if (u < end) {
                float2 A = ((const float2*)X)[(size_t)nbr[u] * 64 + lane];
                a0 += A.x; a1 += A.y;
            }
            unsigned cdeg = end - beg;
            float inv = 1.f / (float)(cdeg ? cdeg : 1u);
            a0 *= inv; a1 *= inv;
        }
        tile[i * 64 + (lane ^ ((i & 7) << 2))] = packbf(a0, a1);
    }
    __syncthreads();

    // GEMM phase
    int row = rbase + ln;
    int rl = row < M ? row : M - 1;
    int swzW = (ln & 7) << 4;
    int swz = (ln & 7) << 2;

    f32x4 acc[8];
#pragma unroll
    for (int cf = 0; cf < 8; ++cf) acc[cf] = ((const f32x4*)bias)[cf * 4 + g];

    const f32x4* xr = (const f32x4*)(X + (size_t)rl * 128);
    unsigned* orow = X2 + (size_t)row * 128;
    i32x4 xpk[4];
#pragma unroll
    for (int ks = 0; ks < 4; ++ks) {
        Frag mf; mf.i = *(const i32x4*)&tile[ln * 64 + ((ks * 16 + g * 4) ^ swz)];
        f32x4 fa = xr[ks * 8 + g * 2], fb = xr[ks * 8 + g * 2 + 1];
        Frag xf;
        i32x4 t = { (int)packbf(fa.x, fa.y), (int)packbf(fa.z, fa.w),
                    (int)packbf(fb.x, fb.y), (int)packbf(fb.z, fb.w) };
        xf.i = t; xpk[ks] = t;
#pragma unroll
        for (int cf = 0; cf < 8; ++cf) {
            int off = (((cf * 16 + ln) << 8) + (ks << 6) + (g << 4)) ^ swzW;
            Frag wa; wa.i = *(const i32x4*)(sW + off);
            Frag wb; wb.i = *(const i32x4*)(sW + 32768 + off);
            acc[cf] = __builtin_amdgcn_mfma_f32_16x16x32_bf16(wa.v, mf.v, acc[cf], 0, 0, 0);
            acc[cf] = __builtin_amdgcn_mfma_f32_16x16x32_bf16(wb.v, xf.v, acc[cf], 0, 0, 0);
        }
    }

    if (row < M) {
#pragma unroll
        for (int ks = 0; ks < 4; ++ks) {
            int p0 = 16 * ks + 4 * g;
            orow[(p0 + 0) * 2] = (unsigned)xpk[ks][0];
            orow[(p0 + 1) * 2] = (unsigned)xpk[ks][1];
            orow[(p0 + 2) * 2] = (unsigned)xpk[ks][2];
            orow[(p0 + 3) * 2] = (unsigned)xpk[ks][3];
        }
#pragma unroll
        for (int cf = 0; cf < 8; ++cf) {
            int p = cf * 8 + g * 2;
            orow[p * 2 + 1]       = packbf(fmaxf(acc[cf][0], 0.f), fmaxf(acc[cf][1], 0.f));
            orow[(p + 1) * 2 + 1] = packbf(fmaxf(acc[cf][2], 0.f), fmaxf(acc[cf][3], 0.f));
        }
    }
}

// ---------------- merged rh gather: chunk-8 MLP, XCD-swizzled ----------------
__global__ __launch_bounds__(256) void aggMean2_kernel(
    const unsigned* __restrict__ X2, const unsigned* __restrict__ rp,
    const int* __restrict__ nbr,
    unsigned* __restrict__ meanXrh, unsigned* __restrict__ meanH)
{
    int wave = threadIdx.x >> 6, lane = threadIdx.x & 63;
    int bid = (blockIdx.x & 7) * 6250 + (blockIdx.x >> 3);   // grid = 50000
    int r = bid * 4 + wave;
    unsigned beg = rp[r], end = rp[r + 1];
    float a0 = 0.f, a1 = 0.f, a2 = 0.f, a3 = 0.f;
    unsigned u = beg;
    for (; u + 8 <= end; u += 8) {
        int j[8];
#pragma unroll
        for (int k = 0; k < 8; ++k) j[k] = nbr[u + k];
        u32x2 A[8];
#pragma unroll
        for (int k = 0; k < 8; ++k)
            A[k] = *(const u32x2*)(X2 + (size_t)j[k] * 128 + lane * 2);
#pragma unroll
        for (int k = 0; k < 8; ++k) {
            a0 += bflo(A[k].x); a1 += bfhi(A[k].x);
            a2 += bflo(A[k].y); a3 += bfhi(A[k].y);
        }
    }
    for (; u + 2 <= end; u += 2) {
        int j0 = nbr[u], j1 = nbr[u + 1];
        u32x2 A = *(const u32x2*)(X2 + (size_t)j0 * 128 + lane * 2);
        u32x2 B = *(const u32x2*)(X2 + (size_t)j1 * 128 + lane * 2);
        a0 += bflo(A.x) + bflo(B.x); a1 += bfhi(A.x) + bfhi(B.x);
        a2 += bflo(A.y) + bflo(B.y); a3 += bfhi(A.y) + bfhi(B.y);
    }
    if (u < end) {
        u32x2 A = *(const u32x2*)(X2 + (size_t)nbr[u] * 128 + lane * 2);
        a0 += bflo(A.x); a1 += bfhi(A.x); a2 += bflo(A.y); a3 += bfhi(A.y);
    }
    unsigned c = end - beg;
    float inv = 1.f / (float)(c ? c : 1u);
    meanXrh[(size_t)r * 64 + lane] = packbf(a0 * inv, a1 * inv);
    meanH[(size_t)r * 64 + lane]   = packbf(a2 * inv, a3 * inv);
}

// ---------------- megaTail: sotu_h (LDS tiles) -> h2 (in-place) -> out ----------------
__global__ __launch_bounds__(1024) void megaTail_kernel(
    const unsigned* __restrict__ meanXrh, const float* __restrict__ xs,
    const unsigned* __restrict__ meanH,
    const unsigned short* __restrict__ Wt2l, const unsigned short* __restrict__ Wt2r,
    const unsigned short* __restrict__ Wt3l, const unsigned short* __restrict__ Wt3r,
    const unsigned short* __restrict__ Wtlin,
    const float* __restrict__ b2, const float* __restrict__ b3,
    const float* __restrict__ blin, float* __restrict__ out, int M)
{
    __shared__ char sW[65536];
    __shared__ unsigned tiles[16 * 1024];
    int tid = threadIdx.x;
    int wave = tid >> 6, lane = tid & 63;
    int ln = lane & 15, g = lane >> 4;
    int row = blockIdx.x * 256 + wave * 16 + ln;
    int rl = row < M ? row : M - 1;
    int swzW = (ln & 7) << 4;
    int swz = (ln & 7) << 2;
    unsigned* tile = tiles + wave * 1024;

    i32x4 w3pre[4], wlpre;
    w3pre[0] = ((const i32x4*)Wt3l)[tid];
    w3pre[1] = ((const i32x4*)Wt3l)[tid + 1024];
    w3pre[2] = ((const i32x4*)Wt3r)[tid];
    w3pre[3] = ((const i32x4*)Wt3r)[tid + 1024];
    wlpre    = ((const i32x4*)Wtlin)[tid];

    ((i32x4*)sW)[tid]        = ((const i32x4*)Wt2l)[tid];
    ((i32x4*)sW)[tid + 1024] = ((const i32x4*)Wt2l)[tid + 1024];
    ((i32x4*)sW)[tid + 2048] = ((const i32x4*)Wt2r)[tid];
    ((i32x4*)sW)[tid + 3072] = ((const i32x4*)Wt2r)[tid + 1024];
    __syncthreads();   // B1

    // phase A: sotu_h = relu(meanXrh@W2l + x_sotu@W2r + b2) -> tile
    {
        f32x4 acc[8];
#pragma unroll
        for (int cf = 0; cf < 8; ++cf) acc[cf] = ((const f32x4*)b2)[cf * 4 + g];
        const i32x4* a1r = (const i32x4*)(meanXrh + (size_t)rl * 64);
        const f32x4* xr = (const f32x4*)(xs + (size_t)rl * 128);
#pragma unroll
        for (int ks = 0; ks < 4; ++ks) {
            Frag mf; mf.i = a1r[ks * 4 + g];
            f32x4 fa = xr[ks * 8 + g * 2], fb = xr[ks * 8 + g * 2 + 1];
            Frag xf;
            i32x4 t = { (int)packbf(fa.x, fa.y), (int)packbf(fa.z, fa.w),
                        (int)packbf(fb.x, fb.y), (int)packbf(fb.z, fb.w) };
            xf.i = t;
#pragma unroll
            for (int cf = 0; cf < 8; ++cf) {
                int off = (((cf * 16 + ln) << 8) + (ks << 6) + (g << 4)) ^ swzW;
                Frag wa; wa.i = *(const i32x4*)(sW + off);
                Frag wb; wb.i = *(const i32x4*)(sW + 32768 + off);
                acc[cf] = __builtin_amdgcn_mfma_f32_16x16x32_bf16(wa.v, mf.v, acc[cf], 0, 0, 0);
                acc[cf] = __builtin_amdgcn_mfma_f32_16x16x32_bf16(wb.v, xf.v, acc[cf], 0, 0, 0);
            }
        }
#pragma unroll
        for (int cf = 0; cf < 8; ++cf) {
            u32x2 o;
            o.x = packbf(fmaxf(acc[cf][0], 0.f), fmaxf(acc[cf][1], 0.f));
            o.y = packbf(fmaxf(acc[cf][2], 0.f), fmaxf(acc[cf][3], 0.f));
            *(u32x2*)&tile[ln * 64 + ((cf * 8 + g * 2) ^ swz)] = o;
        }
    }

    i32x4 mh[4];
    {
        const i32x4* hr = (const i32x4*)(meanH + (size_t)rl * 64);
#pragma unroll
        for (int ks = 0; ks < 4; ++ks) mh[ks] = hr[ks * 4 + g];
    }
    __syncthreads();   // B2
    ((i32x4*)sW)[tid]        = w3pre[0];
    ((i32x4*)sW)[tid + 1024] = w3pre[1];
    ((i32x4*)sW)[tid + 2048] = w3pre[2];
    ((i32x4*)sW)[tid + 3072] = w3pre[3];
    __syncthreads();   // B3

    // phase B: h2 = relu(meanH@W3l + sotu_h@W3r + b3) -> tile (in place)
    {
        f32x4 acc2[8];
#pragma unroll
        for (int cf = 0; cf < 8; ++cf) acc2[cf] = ((const f32x4*)b3)[cf * 4 + g];
#pragma unroll
        for (int ks = 0; ks < 4; ++ks) {
            Frag mf; mf.i = mh[ks];
            Frag sf; sf.i = *(const i32x4*)&tile[ln * 64 + ((ks * 16 + g * 4) ^ swz)];
#pragma unroll
            for (int cf = 0; cf < 8; ++cf) {
                int off = (((cf * 16 + ln) << 8) + (ks << 6) + (g << 4)) ^ swzW;
                Frag wl; wl.i = *(const i32x4*)(sW + off);
                Frag wr; wr.i = *(const i32x4*)(sW + 32768 + off);
                acc2[cf] = __builtin_amdgcn_mfma_f32_16x16x32_bf16(wl.v, mf.v, acc2[cf], 0, 0, 0);
                acc2[cf] = __builtin_amdgcn_mfma_f32_16x16x32_bf16(wr.v, sf.v, acc2[cf], 0, 0, 0);
            }
        }
#pragma unroll
        for (int cf = 0; cf < 8; ++cf) {
            u32x2 o;
            o.x = packbf(fmaxf(acc2[cf][0], 0.f), fmaxf(acc2[cf][1], 0.f));
            o.y = packbf(fmaxf(acc2[cf][2], 0.f), fmaxf(acc2[cf][3], 0.f));
            *(u32x2*)&tile[ln * 64 + ((cf * 8 + g * 2) ^ swz)] = o;
        }
    }
    __syncthreads();   // B4
    ((i32x4*)sW)[tid] = wlpre;
    __syncthreads();   // B5

    // phase C: out = h2 @ Wlin + blin
    f32x4 aL[4];
#pragma unroll
    for (int cf = 0; cf < 4; ++cf) aL[cf] = ((const f32x4*)blin)[cf * 4 + g];
#pragma unroll
    for (int ks = 0; ks < 4; ++ks) {
        Frag hf; hf.i = *(const i32x4*)&tile[ln * 64 + ((ks * 16 + g * 4) ^ swz)];
#pragma unroll
        for (int cf = 0; cf < 4; ++cf) {
            int off = (((cf * 16 + ln) << 8) + (ks << 6) + (g << 4)) ^ swzW;
            Frag wf; wf.i = *(const i32x4*)(sW + off);
            aL[cf] = __builtin_amdgcn_mfma_f32_16x16x32_bf16(wf.v, hf.v, aL[cf], 0, 0, 0);
        }
    }
    if (row < M) {
        float* orow = out + (size_t)row * OUTC;
#pragma unroll
        for (int cf = 0; cf < 4; ++cf)
            *(f32x4*)(orow + cf * 16 + g * 4) = aL[cf];
    }
}

extern "C" void kernel_launch(void* const* d_in, const int* in_sizes, int n_in,
                              void* d_out, int out_size, void* d_ws, size_t ws_size,
                              hipStream_t stream)
{
    const float* x_taxon = (const float*)d_in[0];
    const float* x_sotu  = (const float*)d_in[1];
    const int* hp_src = (const int*)d_in[2];
    const int* hp_dst = (const int*)d_in[3];
    const int* rh_src = (const int*)d_in[4];
    const int* rh_dst = (const int*)d_in[5];
    const float* W1l = (const float*)d_in[6];
    const float* W1r = (const float*)d_in[7];
    const float* b1  = (const float*)d_in[8];
    const float* W2l = (const float*)d_in[9];
    const float* W2r = (const float*)d_in[10];
    const float* b2  = (const float*)d_in[11];
    const float* W3l = (const float*)d_in[12];
    const float* W3r = (const float*)d_in[13];
    const float* b3  = (const float*)d_in[14];
    const float* Wlin = (const float*)d_in[15];
    const float* blin = (const float*)d_in[16];
    float* out = (float*)d_out;

    // ---- workspace layout (bytes) ----
    char* ws = (char*)d_ws;
    unsigned* X2      = (unsigned*)(ws);                  // [100K][128] xt|taxon_h interleaved
    unsigned* meanXrh = (unsigned*)(ws + 51200000);       // [200K][64]; ebuf overlays (dead first)
    unsigned* meanH   = (unsigned*)(ws + 102400000);      // [200K][64]
    unsigned* ebuf    = (unsigned*)(ws + 51200000);       // [147*24576] u32 = 14.5MB, dead before aggMean2
    int*      sorted_all = (int*)(ws + 179200000);        // [E_ALL] 8.8MB
    unsigned* row_ptr = (unsigned*)(ws + 188000000);      // [300001]
    unsigned* bcnt    = (unsigned*)(ws + 189200128);      // [160]
    unsigned* bstart  = (unsigned*)(ws + 189200768);      // [160]
    unsigned short* wtbase = (unsigned short*)(ws + 189201408);
    unsigned short* Wt1l = wtbase;
    unsigned short* Wt1r = wtbase + 16384;
    unsigned short* Wt2l = wtbase + 32768;
    unsigned short* Wt2r = wtbase + 49152;
    unsigned short* Wt3l = wtbase + 65536;
    unsigned short* Wt3r = wtbase + 81920;
    unsigned short* Wtlin = wtbase + 98304;

    // zero bcnt only
    hipMemsetAsync(bcnt, 0, 640, stream);

    // ---- weight prep (independent) ----
    wprep_all_kernel<<<(6 * 16384 + 8192 + 255) / 256, 256, 0, stream>>>(
        W1l, W1r, W2l, W2r, W3l, W3r, Wlin, wtbase);

    // ---- unified CSR build (fixed-capacity buckets, no count pass) ----
    partition_kernel<<<(E_ALL + 4095) / 4096, 256, 0, stream>>>(
        hp_src, hp_dst, rh_src, rh_dst, bcnt, ebuf);
    scan147_kernel<<<1, 256, 0, stream>>>(bcnt, bstart, row_ptr);
    fillB_kernel<<<NBUCK, 256, 0, stream>>>(ebuf, bcnt, bstart, row_ptr, sorted_all);

    // ---- fused hp-mean + taxon_h GEMM -> full X2 rows ----
    gemmTh2_kernel<<<(N_TAXON + 255) / 256, 1024, 0, stream>>>(
        x_taxon, row_ptr, sorted_all, Wt1l, Wt1r, b1, X2, N_TAXON);

    // ---- merged rh gather: meanXrh + meanH in one walk (chunk-8) ----
    aggMean2_kernel<<<N_SOTU / 4, 256, 0, stream>>>(
        X2, row_ptr + N_TAXON, sorted_all, meanXrh, meanH);

    // ---- megaTail: sotu_h -> h2 (LDS) -> out ----
    megaTail_kernel<<<(N_SOTU + 255) / 256, 1024, 0, stream>>>(
        meanXrh, x_sotu, meanH, Wt2l, Wt2r, Wt3l, Wt3r, Wtlin, b2, b3, blin, out, N_SOTU);
}